// Round 2
// baseline (608.467 us; speedup 1.0000x reference)
//
#include <hip/hip_runtime.h>
#include <hip/hip_bf16.h>
#include <math.h>

#define G_GRAPHS 256
#define EPG 2048
#define E_TOT 524288
#define HF 256
#define FIN 128

// ============================================================================
__global__ void init_cur(int* __restrict__ cur) {
    int i = blockIdx.x * blockDim.x + threadIdx.x;
    if (i < G_GRAPHS * 256) cur[i] = i & 255;
}

// ---------------------------------------------------------------------------
// C[N x 256] = A[N x K] @ W[K x 256], fp32, k-ascending single-accumulator
// chains (bit-exact vs all previous versions).
// v5: TM x 128 tile (TM=128 or 64), RM x 8 per thread, BK=32.
//   * A in LDS, TRANSPOSED As[kk][row'] with kq-XOR swizzle
//     row' = row ^ ((k>>2)<<3): staging writes 2-way (free), compute
//     ds_read_b128 conflict-free. Verified bank math in journal.
//   * W NOT staged: read straight from global. W tile is 16KB -> L1-resident;
//     per-wave read = 16 distinct 32B segments (broadcast x4). This HALVES
//     LDS traffic per FMA (2 b128/kk vs 4) -- the R1 kernel was LDS-BW-bound
//     (24.6k cy LDS vs 16.4k cy FMA per CU-tile).
//   * LDS 17KB -> more blocks/CU; cross-block overlap hides barriers.
// ---------------------------------------------------------------------------
template <int K, int TM>
__global__ __launch_bounds__(256, 4)
void gemm_v5(const float* __restrict__ A, const float* __restrict__ W,
             float* __restrict__ C) {
    constexpr int RM = TM / 16;                   // rows per thread: 8 or 4
    constexpr int AST = (TM == 128) ? 132 : 68;   // padded row capacity
    __shared__ __align__(16) float As[32 * AST];
    const int tid = threadIdx.x;
    const int tx = tid & 15;    // cols c0 + tx*8 .. +7
    const int ty = tid >> 4;    // rows r0 + ty*RM .. +RM-1
    const int r0 = blockIdx.x * TM;
    const int c0 = blockIdx.y * 128;
    float acc[RM][8] = {};
    const int l8 = tid >> 3;    // row-within-32-slab
    const int kq = tid & 7;     // float4 index along k
    for (int k0 = 0; k0 < K; k0 += 32) {
        // stage A: TM rows x 32 kk, transposed + swizzled
        constexpr int ITS = TM / 32;
#pragma unroll
        for (int it = 0; it < ITS; ++it) {
            int row = it * 32 + l8;
            float4 v = *(const float4*)&A[(size_t)(r0 + row) * K + k0 + 4 * kq];
            int rs = row ^ (kq << 3);
            As[(4 * kq + 0) * AST + rs] = v.x;
            As[(4 * kq + 1) * AST + rs] = v.y;
            As[(4 * kq + 2) * AST + rs] = v.z;
            As[(4 * kq + 3) * AST + rs] = v.w;
        }
        __syncthreads();
        const float* Wp = &W[(size_t)k0 * 256 + c0 + tx * 8];
#pragma unroll 4
        for (int kk = 0; kk < 32; ++kk) {
            const float4 w0 = *(const float4*)&Wp[kk * 256];
            const float4 w1 = *(const float4*)&Wp[kk * 256 + 4];
            const int kqq = kk >> 2;
            float av[RM];
            if constexpr (TM == 128) {
                const int g = (ty ^ kqq) << 3;
                const float4 a0 = *(const float4*)&As[kk * AST + g];
                const float4 a1 = *(const float4*)&As[kk * AST + g + 4];
                av[0] = a0.x; av[1] = a0.y; av[2] = a0.z; av[3] = a0.w;
                av[4] = a1.x; av[5] = a1.y; av[6] = a1.z; av[7] = a1.w;
            } else {
                const int g = 4 * (ty ^ (2 * kqq));
                const float4 a0 = *(const float4*)&As[kk * AST + g];
                av[0] = a0.x; av[1] = a0.y; av[2] = a0.z; av[3] = a0.w;
            }
            const float wv_[8] = {w0.x, w0.y, w0.z, w0.w, w1.x, w1.y, w1.z, w1.w};
#pragma unroll
            for (int i = 0; i < RM; ++i)
#pragma unroll
                for (int j = 0; j < 8; ++j)
                    acc[i][j] += av[i] * wv_[j];
        }
        __syncthreads();
    }
#pragma unroll
    for (int i = 0; i < RM; ++i) {
        float4 v0 = make_float4(acc[i][0], acc[i][1], acc[i][2], acc[i][3]);
        float4 v1 = make_float4(acc[i][4], acc[i][5], acc[i][6], acc[i][7]);
        size_t base = (size_t)(r0 + ty * RM + i) * 256 + c0 + tx * 8;
        *(float4*)&C[base] = v0;
        *(float4*)&C[base + 4] = v1;
    }
}

// ---------------------------------------------------------------------------
// Parallel STABLE counting-sort CSR with packed (src, dinv_src) slots.
// ---------------------------------------------------------------------------
__global__ __launch_bounds__(256)
void csr_build(const int* __restrict__ ei, const int* __restrict__ cur, int npg,
               int* __restrict__ degS, float* __restrict__ dinvS,
               int* __restrict__ startsS, int2* __restrict__ slots2) {
    __shared__ int cul[EPG];
    __shared__ short dstv[EPG];
    __shared__ unsigned char rnk[EPG];
    __shared__ int h[32][256];
    __shared__ int cnt[256];
    __shared__ int st[256];
    const int g = blockIdx.x;
    const int t = threadIdx.x;
    const int lane = t & 63;
    const int wv = t >> 6;

    for (int i = t; i < 32 * 256; i += 256) ((int*)h)[i] = 0;
    for (int e = t; e < EPG; e += 256) {
        size_t idx = (size_t)g * EPG + e;
        int cu = cur[g * 256 + (ei[idx] - g * 256)];
        int cv = cur[g * 256 + (ei[E_TOT + idx] - g * 256)];
        bool valid = (cu >= 0 && cv >= 0);
        cul[e] = cu;
        dstv[e] = valid ? (short)cv : (short)256;
    }
    __syncthreads();
    for (int c = wv; c < 32; c += 4) {
        int e = c * 64 + lane;
        int d = (int)dstv[e];
        unsigned long long m = ~0ULL;
#pragma unroll
        for (int b = 0; b < 9; ++b) {
            unsigned long long bb = __ballot((d >> b) & 1);
            m &= ((d >> b) & 1) ? bb : ~bb;
        }
        int r = __popcll(m & ((1ULL << lane) - 1ULL));
        rnk[e] = (unsigned char)r;
        if (r == 0 && d < 256) h[c][d] = __popcll(m);
    }
    __syncthreads();
    if (t < npg) {
        int run = 0;
        for (int c = 0; c < 32; ++c) { int v = h[c][t]; h[c][t] = run; run += v; }
        cnt[t] = run;
        degS[g * npg + t] = run + 1;
        dinvS[g * npg + t] = 1.0f / sqrtf((float)(run + 1));
    }
    __syncthreads();
    if (t == 0) {
        int run = 0;
        for (int i = 0; i < npg; ++i) { st[i] = run; run += cnt[i]; }
    }
    __syncthreads();
    if (t < npg) startsS[g * npg + t] = g * EPG + st[t];
    for (int e = t; e < EPG; e += 256) {
        int d = (int)dstv[e];
        if (d < npg) {
            int slot = st[d] + h[e >> 6][d] + (int)rnk[e];
            int cu = cul[e];
            float dv = 1.0f / sqrtf((float)(cnt[cu] + 1));   // == dinvS[src]
            slots2[g * EPG + slot] = make_int2(g * npg + cu, __float_as_int(dv));
        }
    }
}

// ---------------------------------------------------------------------------
// conv + relu + pool score, v2: ONE WAVE PER NODE, float4 per lane.
// 4x fewer VMEM instructions and 4x bytes-in-flight per issue slot vs the
// block-per-node version (which was L2-latency-bound at 7.3 TB/s effective).
// Bit-exact: per-feature accumulation chain identical (same edge order, same
// expression); score phase bounces v through a per-wave LDS slice and re-reads
// features t, t+64, t+128, t+192 with the exact original per-lane sum order
// and shfl tree. No __syncthreads anywhere -- waves fully independent.
// ---------------------------------------------------------------------------
__global__ __launch_bounds__(256)
void agg_score2(const int* __restrict__ degS, const float* __restrict__ dinvS,
                const int* __restrict__ startsS, const int2* __restrict__ slots2,
                const float* __restrict__ HL, float* __restrict__ H2,
                const float* __restrict__ bias, const float* __restrict__ pw,
                float* __restrict__ score, int nbOver8) {
    __shared__ float vrow[4][256];
    const int t = threadIdx.x;
    const int wv = t >> 6;
    const int lane = t & 63;
    const int blk = (blockIdx.x & 7) * nbOver8 + (blockIdx.x >> 3);
    const int node = blk * 4 + wv;
    const int cntE = degS[node] - 1;
    const float degF = (float)(cntE + 1);
    const float dn = dinvS[node];
    const int2* sl = slots2 + startsS[node];
    float ax = 0.f, ay = 0.f, az = 0.f, aw = 0.f;
    int j = 0;
    for (; j + 8 <= cntE; j += 8) {
        int2 s[8];
#pragma unroll
        for (int u = 0; u < 8; ++u) s[u] = sl[j + u];
        float4 hv[8];
#pragma unroll
        for (int u = 0; u < 8; ++u)
            hv[u] = *(const float4*)&HL[(size_t)s[u].x * 256 + 4 * lane];
#pragma unroll
        for (int u = 0; u < 8; ++u) {
            float dv = __int_as_float(s[u].y);
            ax += dv * hv[u].x; ay += dv * hv[u].y;
            az += dv * hv[u].z; aw += dv * hv[u].w;
        }
    }
    for (; j + 4 <= cntE; j += 4) {
        int2 s[4];
#pragma unroll
        for (int u = 0; u < 4; ++u) s[u] = sl[j + u];
        float4 hv[4];
#pragma unroll
        for (int u = 0; u < 4; ++u)
            hv[u] = *(const float4*)&HL[(size_t)s[u].x * 256 + 4 * lane];
#pragma unroll
        for (int u = 0; u < 4; ++u) {
            float dv = __int_as_float(s[u].y);
            ax += dv * hv[u].x; ay += dv * hv[u].y;
            az += dv * hv[u].z; aw += dv * hv[u].w;
        }
    }
    for (; j < cntE; ++j) {
        int2 sv = sl[j];
        float dv = __int_as_float(sv.y);
        float4 hv = *(const float4*)&HL[(size_t)sv.x * 256 + 4 * lane];
        ax += dv * hv.x; ay += dv * hv.y; az += dv * hv.z; aw += dv * hv.w;
    }
    const float4 hn = *(const float4*)&HL[(size_t)node * 256 + 4 * lane];
    const float4 bi = *(const float4*)&bias[4 * lane];
    float4 v;
    v.x = ax * dn + hn.x / degF + bi.x;  v.x = fmaxf(v.x, 0.f);
    v.y = ay * dn + hn.y / degF + bi.y;  v.y = fmaxf(v.y, 0.f);
    v.z = az * dn + hn.z / degF + bi.z;  v.z = fmaxf(v.z, 0.f);
    v.w = aw * dn + hn.w / degF + bi.w;  v.w = fmaxf(v.w, 0.f);
    *(float4*)&H2[(size_t)node * 256 + 4 * lane] = v;
    *(float4*)&vrow[wv][4 * lane] = v;
    // same-wave LDS RAW: compiler inserts the lgkmcnt; no cross-wave sharing.
    float pr = 0.f, s2p = 0.f;
    for (int jj = 0; jj < 4; ++jj) {
        int f = lane + 64 * jj;
        float w = pw[f];
        pr += vrow[wv][f] * w;
        s2p += w * w;
    }
    for (int off = 32; off; off >>= 1) {
        pr += __shfl_down(pr, off, 64);
        s2p += __shfl_down(s2p, off, 64);
    }
    s2p = __shfl(s2p, 0, 64);
    if (lane == 0) score[node] = tanhf(pr / sqrtf(s2p));
}

// ---------------------------------------------------------------------------
__global__ __launch_bounds__(256)
void topk_cur(const float* __restrict__ score, int npg, int k,
              int* __restrict__ kept, int* __restrict__ cur) {
    __shared__ float ss[256];
    __shared__ int si_[256];
    __shared__ int rankOf[256];
    const int g = blockIdx.x;
    const int t = threadIdx.x;
    if (t < npg) { ss[t] = score[g * npg + t]; si_[t] = t; }
    else         { ss[t] = -INFINITY; si_[t] = 0x7FFFFFFF; }
    for (int size = 2; size <= 256; size <<= 1) {
        for (int stride = size >> 1; stride > 0; stride >>= 1) {
            __syncthreads();
            int i = t, j = t ^ stride;
            if (j > i) {
                float a = ss[i], b = ss[j];
                int ia = si_[i], ib = si_[j];
                bool inOrder = (a > b) || (a == b && ia < ib);
                bool desc = ((i & size) == 0);
                if (desc ? !inOrder : inOrder) {
                    ss[i] = b; ss[j] = a; si_[i] = ib; si_[j] = ia;
                }
            }
        }
    }
    __syncthreads();
    rankOf[t] = -1;
    __syncthreads();
    if (t < k) {
        kept[g * k + t] = g * npg + si_[t];
        rankOf[si_[t]] = t;
    }
    __syncthreads();
    {
        int v = g * 256 + t;
        int c = cur[v];
        cur[v] = (c >= 0) ? rankOf[c] : -1;
    }
}

__global__ __launch_bounds__(256)
void pool_gather(const int* __restrict__ kept, const float* __restrict__ score,
                 const float* __restrict__ H2, float* __restrict__ OUT) {
    const int j = blockIdx.x;
    const int t = threadIdx.x;
    const int o = kept[j];
    OUT[(size_t)j * 256 + t] = H2[(size_t)o * 256 + t] * score[o];
}

__global__ __launch_bounds__(256)
void readout(const float* __restrict__ X, int k, float* __restrict__ outacc,
             int first) {
    const int g = blockIdx.x;
    const int t = threadIdx.x;
    const float* base = X + (size_t)g * k * 256 + t;
    float mx = -INFINITY, sm = 0.f;
    for (int n = 0; n < k; ++n) {
        float vv = base[(size_t)n * 256];
        mx = fmaxf(mx, vv);
        sm += vv;
    }
    float mean = sm / (float)k;
    if (first) {
        outacc[g * 512 + t] = mx;
        outacc[g * 512 + 256 + t] = mean;
    } else {
        outacc[g * 512 + t] += mx;
        outacc[g * 512 + 256 + t] += mean;
    }
}

__global__ __launch_bounds__(256)
void mlp_head(const float* __restrict__ outacc,
              const float* __restrict__ l1w, const float* __restrict__ l1b,
              const float* __restrict__ l2w, const float* __restrict__ l2b,
              const float* __restrict__ l3w, const float* __restrict__ l3b,
              float* __restrict__ out) {
    __shared__ float row[512];
    __shared__ float h1[256];
    __shared__ float h2[128];
    const int g = blockIdx.x;
    const int t = threadIdx.x;
    row[t] = outacc[g * 512 + t];
    row[256 + t] = outacc[g * 512 + 256 + t];
    __syncthreads();
    {
        float a = l1b[t];
        for (int j = 0; j < 512; ++j) a += row[j] * l1w[j * 256 + t];
        h1[t] = fmaxf(a, 0.f);
    }
    __syncthreads();
    if (t < 128) {
        float a2 = l2b[t];
        for (int j = 0; j < 256; ++j) a2 += h1[j] * l2w[j * 128 + t];
        h2[t] = fmaxf(a2, 0.f);
    }
    __syncthreads();
    if (t == 0) {
        float l0 = l3b[0], l1 = l3b[1];
        for (int j = 0; j < 128; ++j) {
            float h = h2[j];
            l0 += h * l3w[j * 2 + 0];
            l1 += h * l3w[j * 2 + 1];
        }
        float m = fmaxf(l0, l1);
        float lse = m + logf(expf(l0 - m) + expf(l1 - m));
        out[g * 2 + 0] = l0 - lse;
        out[g * 2 + 1] = l1 - lse;
    }
}

// ============================================================================
// Fallback: proven R15 monolith (used only if ws_size is too small)
// ============================================================================
__global__ __launch_bounds__(256, 1)
void gnn_mono(const float* __restrict__ x, const int* __restrict__ ei,
              const float* __restrict__ gw0, const float* __restrict__ gb0,
              const float* __restrict__ gw1, const float* __restrict__ gb1,
              const float* __restrict__ gw2, const float* __restrict__ gb2,
              const float* __restrict__ pw0, const float* __restrict__ pw1,
              const float* __restrict__ pw2,
              const float* __restrict__ l1w, const float* __restrict__ l1b,
              const float* __restrict__ l2w, const float* __restrict__ l2b,
              const float* __restrict__ l3w, const float* __restrict__ l3b,
              float* __restrict__ out, float* __restrict__ ws) {
    const int g = blockIdx.x;
    const int t = threadIdx.x;
    float* P = ws + (size_t)g * HF * 256;
    float* Q = ws + (size_t)G_GRAPHS * HF * 256 + (size_t)g * HF * 256;
    __shared__ int   eb[EPG];
    __shared__ int   slots[EPG];
    __shared__ int   curID[256];
    __shared__ int   cntL[256];
    __shared__ int   startL[256];
    __shared__ float degF[256];
    __shared__ float dinv[256];
    __shared__ float sa[256];
    __shared__ float ss[256];
    __shared__ int   si_[256];
    __shared__ float scoreV[256];
    __shared__ int   kept[128];
    __shared__ int   rankOf[256];
    __shared__ float row[512];
    for (int e = t; e < EPG; e += 256) {
        size_t idx = (size_t)g * EPG + e;
        eb[e] = ((ei[idx] - g * 256) << 8) | (ei[E_TOT + idx] - g * 256);
    }
    curID[t] = t;
    float accMx = 0.f, accMn = 0.f;
    const float* GW[3] = {gw0, gw1, gw2};
    const float* GB[3] = {gb0, gb1, gb2};
    const float* PW[3] = {pw0, pw1, pw2};
    const int kk[3] = {128, 64, 32};
    int npg = 256;
    __syncthreads();
    for (int s = 0; s < 3; ++s) {
        const int knext = kk[s];
        {
            const float* Wp = GW[s];
            const int K = (s == 0) ? FIN : HF;
            for (int n = 0; n < npg; ++n) {
                if (s == 0) { if (t < FIN) sa[t] = x[(size_t)(g * 256 + n) * FIN + t]; }
                else sa[t] = P[(size_t)n * HF + t];
                __syncthreads();
                float a = 0.f;
                for (int k2 = 0; k2 < K; ++k2) a += sa[k2] * Wp[k2 * HF + t];
                Q[(size_t)n * HF + t] = a;
                __syncthreads();
            }
        }
        cntL[t] = 0;
        __syncthreads();
        for (int e = t; e < EPG; e += 256) {
            int p = eb[e];
            int cu = curID[p >> 8], cv = curID[p & 255];
            if (cu >= 0 && cv >= 0) atomicAdd(&cntL[cv], 1);
        }
        __syncthreads();
        if (t == 0) { int run = 0; for (int i = 0; i < npg; ++i) { startL[i] = run; run += cntL[i]; } }
        __syncthreads();
        if (t < npg) {
            float d = (float)cntL[t] + 1.0f;
            degF[t] = d;
            dinv[t] = 1.0f / sqrtf(d);
            int c = startL[t];
            for (int e = 0; e < EPG; ++e) {
                int p = eb[e];
                int cu = curID[p >> 8], cv = curID[p & 255];
                if (cu >= 0 && cv >= 0 && cv == t) slots[c++] = e;
            }
        }
        __syncthreads();
        {
            const float bb = GB[s][t];
            for (int n = 0; n < npg; ++n) {
                float acc = 0.f;
                const int s0 = startL[n], s1 = s0 + cntL[n];
                for (int j = s0; j < s1; ++j) {
                    int scur = curID[eb[slots[j]] >> 8];
                    acc += dinv[scur] * Q[(size_t)scur * HF + t];
                }
                float v = acc * dinv[n] + Q[(size_t)n * HF + t] / degF[n] + bb;
                P[(size_t)n * HF + t] = fmaxf(v, 0.f);
            }
        }
        __syncthreads();
        {
            const float* pwp = PW[s];
            const int lane = t & 63, wv = t >> 6;
            float s2p = 0.f;
            for (int j = 0; j < 4; ++j) { float w = pwp[lane + 64 * j]; s2p += w * w; }
            for (int off = 32; off; off >>= 1) s2p += __shfl_down(s2p, off, 64);
            s2p = __shfl(s2p, 0, 64);
            const float nw = sqrtf(s2p);
            for (int n = wv; n < npg; n += 4) {
                float pr = 0.f;
                for (int j = 0; j < 4; ++j) { int f = lane + 64 * j; pr += P[(size_t)n * HF + f] * pwp[f]; }
                for (int off = 32; off; off >>= 1) pr += __shfl_down(pr, off, 64);
                if (lane == 0) scoreV[n] = tanhf(pr / nw);
            }
        }
        __syncthreads();
        if (t < npg) { ss[t] = scoreV[t]; si_[t] = t; }
        else         { ss[t] = -INFINITY; si_[t] = 0x7FFFFFFF; }
        for (int size = 2; size <= 256; size <<= 1) {
            for (int stride = size >> 1; stride > 0; stride >>= 1) {
                __syncthreads();
                int i = t, j = t ^ stride;
                if (j > i) {
                    float a = ss[i], b = ss[j];
                    int ia = si_[i], ib = si_[j];
                    bool inOrder = (a > b) || (a == b && ia < ib);
                    bool desc = ((i & size) == 0);
                    if (desc ? !inOrder : inOrder) { ss[i] = b; ss[j] = a; si_[i] = ib; si_[j] = ia; }
                }
            }
        }
        __syncthreads();
        if (t < knext) kept[t] = si_[t];
        __syncthreads();
        {
            float mx = -INFINITY, sm = 0.f;
            for (int n = 0; n < knext; ++n) {
                int o = kept[n];
                float vv = P[(size_t)o * HF + t] * scoreV[o];
                Q[(size_t)n * HF + t] = vv;
                mx = fmaxf(mx, vv);
                sm += vv;
            }
            accMx += mx;
            accMn += sm / (float)knext;
        }
        rankOf[t] = -1;
        __syncthreads();
        if (t < knext) rankOf[kept[t]] = t;
        __syncthreads();
        { int c = curID[t]; curID[t] = (c >= 0) ? rankOf[c] : -1; }
        __syncthreads();
        { float* tmp = P; P = Q; Q = tmp; }
        npg = knext;
    }
    row[t] = accMx;
    row[256 + t] = accMn;
    __syncthreads();
    { float a = l1b[t]; for (int j = 0; j < 512; ++j) a += row[j] * l1w[j * 256 + t]; scoreV[t] = fmaxf(a, 0.f); }
    __syncthreads();
    if (t < 128) { float a2 = l2b[t]; for (int j = 0; j < 256; ++j) a2 += scoreV[j] * l2w[j * 128 + t]; sa[t] = fmaxf(a2, 0.f); }
    __syncthreads();
    if (t == 0) {
        float l0 = l3b[0], l1 = l3b[1];
        for (int j = 0; j < 128; ++j) { float h = sa[j]; l0 += h * l3w[j * 2 + 0]; l1 += h * l3w[j * 2 + 1]; }
        float m = fmaxf(l0, l1);
        float lse = m + logf(expf(l0 - m) + expf(l1 - m));
        out[g * 2 + 0] = l0 - lse;
        out[g * 2 + 1] = l1 - lse;
    }
}

// ============================================================================
extern "C" void kernel_launch(void* const* d_in, const int* in_sizes, int n_in,
                              void* d_out, int out_size, void* d_ws, size_t ws_size,
                              hipStream_t stream) {
    const float* x   = (const float*)d_in[0];
    const int*   ei  = (const int*)d_in[1];
    const float* gw0 = (const float*)d_in[3];
    const float* gb0 = (const float*)d_in[4];
    const float* gw1 = (const float*)d_in[5];
    const float* gb1 = (const float*)d_in[6];
    const float* gw2 = (const float*)d_in[7];
    const float* gb2 = (const float*)d_in[8];
    const float* pw0 = (const float*)d_in[9];
    const float* pw1 = (const float*)d_in[10];
    const float* pw2 = (const float*)d_in[11];
    const float* l1w = (const float*)d_in[12];
    const float* l1b = (const float*)d_in[13];
    const float* l2w = (const float*)d_in[14];
    const float* l2b = (const float*)d_in[15];
    const float* l3w = (const float*)d_in[16];
    const float* l3b = (const float*)d_in[17];
    float* out = (float*)d_out;

    const size_t SLAB = (size_t)65536 * 256;
    char* p = (char*)d_ws;
    float* P      = (float*)p; p += SLAB * 4;
    float* Q      = (float*)p; p += SLAB * 4;
    int*   cur    = (int*)p;   p += (size_t)65536 * 4;
    int*   degS   = (int*)p;   p += (size_t)65536 * 4;
    float* dinvS  = (float*)p; p += (size_t)65536 * 4;
    int*   starts = (int*)p;   p += (size_t)65536 * 4;
    int2*  slots2 = (int2*)p;  p += (size_t)E_TOT * 8;
    float* score  = (float*)p; p += (size_t)65536 * 4;
    int*   kept   = (int*)p;   p += (size_t)32768 * 4;
    float* outacc = (float*)p; p += (size_t)G_GRAPHS * 512 * 4;
    const size_t needed = (size_t)(p - (char*)d_ws);

    if (ws_size < needed) {
        gnn_mono<<<G_GRAPHS, 256, 0, stream>>>(
            x, ei, gw0, gb0, gw1, gb1, gw2, gb2, pw0, pw1, pw2,
            l1w, l1b, l2w, l2b, l3w, l3b, out, (float*)d_ws);
        return;
    }

    init_cur<<<(G_GRAPHS * 256 + 255) / 256, 256, 0, stream>>>(cur);

    const int   npg[3] = {256, 128, 64};
    const int   kk[3]  = {128, 64, 32};
    const int   Ns[3]  = {65536, 32768, 16384};
    const float* GW[3] = {gw0, gw1, gw2};
    const float* GB[3] = {gb0, gb1, gb2};
    const float* PW[3] = {pw0, pw1, pw2};

    float* HLs[3]   = {P, Q, P};
    float* H2s[3]   = {Q, P, Q};
    float* POOLs[3] = {P, Q, P};

    for (int s = 0; s < 3; ++s) {
        const int n = Ns[s];
        const int k = kk[s];
        // 1) GEMM v5: A-in-LDS (swizzled transpose), W-from-global (L1)
        if (s == 0) {
            gemm_v5<FIN, 128><<<dim3(n / 128, 2), 256, 0, stream>>>(x, GW[s], HLs[s]);
        } else {
            gemm_v5<HF, 64><<<dim3(n / 64, 2), 256, 0, stream>>>(POOLs[s - 1], GW[s], HLs[s]);
        }
        // 2) CSR (parallel stable counting sort, packed slots)
        csr_build<<<G_GRAPHS, 256, 0, stream>>>(ei, cur, npg[s],
                                                degS, dinvS, starts, slots2);
        // 3) conv + score v2: wave-per-node, float4 gathers, no barriers
        agg_score2<<<n / 4, 256, 0, stream>>>(degS, dinvS, starts, slots2,
                                              HLs[s], H2s[s], GB[s], PW[s], score,
                                              n / 32);
        // 4) top-k + cur update
        topk_cur<<<G_GRAPHS, 256, 0, stream>>>(score, npg[s], k, kept, cur);
        // 5) pool
        pool_gather<<<G_GRAPHS * k, 256, 0, stream>>>(kept, score, H2s[s], POOLs[s]);
        // 6) readout
        readout<<<G_GRAPHS, 256, 0, stream>>>(POOLs[s], k, outacc, s == 0 ? 1 : 0);
    }

    mlp_head<<<G_GRAPHS, 256, 0, stream>>>(outacc, l1w, l1b, l2w, l2b, l3w, l3b, out);
}

// Round 3
// 531.250 us; speedup vs baseline: 1.1453x; 1.1453x over previous
//
#include <hip/hip_runtime.h>
#include <hip/hip_bf16.h>
#include <math.h>

#define G_GRAPHS 256
#define EPG 2048
#define E_TOT 524288
#define HF 256
#define FIN 128

// ============================================================================
__global__ void init_cur(int* __restrict__ cur) {
    int i = blockIdx.x * blockDim.x + threadIdx.x;
    if (i < G_GRAPHS * 256) cur[i] = i & 255;
}

// ---------------------------------------------------------------------------
// C[N x 256] = A[N x K] @ W[K x 256], fp32, k-ascending single-accumulator
// chains (bit-exact vs all previous versions).
// v6 = v4 compute shape + proven conflict-free LDS layouts:
//   * 128x128 tile, 8x8/thread, BK=32.
//   * A transposed As[kk][row^ (kq<<3)] (v5's layout, bit-exact-proven):
//     staging writes 2-way (free), compute reads 4-distinct-addr broadcast.
//   * W split halves Wa/Wb[32][68] (v3's layout, bit-exact-proven):
//     stride 68 == 4 (mod 32), tx*4 step -> 2-way staging, 2-way+broadcast
//     compute reads. v4's single Ws[...][132] with tx*8 step was a TRUE
//     4-way conflict (tx,tx+4,tx+8,tx+12 same bank, diff addr) -- that was
//     the 27us-wall -> 70us gap. v5's W-from-global was latency-bound (120us).
//   * Thread covers cols {c0+tx*4..+3} and {c0+64+tx*4..+3}.
// ---------------------------------------------------------------------------
template <int K>
__global__ __launch_bounds__(256, 4)
void gemm_v6(const float* __restrict__ A, const float* __restrict__ W,
             float* __restrict__ C) {
    __shared__ __align__(16) float As[32 * 132];
    __shared__ __align__(16) float Wa[32 * 68];
    __shared__ __align__(16) float Wb[32 * 68];
    const int tid = threadIdx.x;
    const int tx = tid & 15;    // col groups: c0 + tx*4, c0 + 64 + tx*4
    const int ty = tid >> 4;    // rows r0 + ty*8 .. +7
    const int r0 = blockIdx.x * 128;
    const int c0 = blockIdx.y * 128;
    float acc[8][8] = {{0.f}};
    const int l8 = tid >> 3;    // 0..31: row-within-slab for A staging
    const int kq = tid & 7;     // float4 index along k for A staging
    for (int k0 = 0; k0 < K; k0 += 32) {
        // stage A: 128 rows x 32 kk, transposed + kq-XOR swizzle
#pragma unroll
        for (int it = 0; it < 4; ++it) {
            int row = it * 32 + l8;
            float4 v = *(const float4*)&A[(size_t)(r0 + row) * K + k0 + 4 * kq];
            int rs = row ^ (kq << 3);
            As[(4 * kq + 0) * 132 + rs] = v.x;
            As[(4 * kq + 1) * 132 + rs] = v.y;
            As[(4 * kq + 2) * 132 + rs] = v.z;
            As[(4 * kq + 3) * 132 + rs] = v.w;
        }
        // stage W: 32 kk x 128 cols -> split halves (stride 68)
#pragma unroll
        for (int it = 0; it < 4; ++it) {
            int idx = it * 256 + tid;      // 0..1023
            int kk = idx >> 5;             // 0..31
            int c = idx & 31;              // float4 col index
            float4 v = *(const float4*)&W[(size_t)(k0 + kk) * 256 + c0 + 4 * c];
            if (c < 16) *(float4*)&Wa[kk * 68 + 4 * c] = v;
            else        *(float4*)&Wb[kk * 68 + 4 * (c - 16)] = v;
        }
        __syncthreads();
#pragma unroll 4
        for (int kk = 0; kk < 32; ++kk) {
            const int kqq = kk >> 2;
            const int g = (ty ^ kqq) << 3;
            const float4 a0 = *(const float4*)&As[kk * 132 + g];
            const float4 a1 = *(const float4*)&As[kk * 132 + g + 4];
            const float4 w0 = *(const float4*)&Wa[kk * 68 + tx * 4];
            const float4 w1 = *(const float4*)&Wb[kk * 68 + tx * 4];
            float av[8] = {a0.x, a0.y, a0.z, a0.w, a1.x, a1.y, a1.z, a1.w};
            float wv_[8] = {w0.x, w0.y, w0.z, w0.w, w1.x, w1.y, w1.z, w1.w};
#pragma unroll
            for (int i = 0; i < 8; ++i)
#pragma unroll
                for (int j = 0; j < 8; ++j)
                    acc[i][j] += av[i] * wv_[j];
        }
        __syncthreads();
    }
#pragma unroll
    for (int i = 0; i < 8; ++i) {
        float4 v0 = make_float4(acc[i][0], acc[i][1], acc[i][2], acc[i][3]);
        float4 v1 = make_float4(acc[i][4], acc[i][5], acc[i][6], acc[i][7]);
        size_t base = (size_t)(r0 + ty * 8 + i) * 256 + c0 + tx * 4;
        *(float4*)&C[base] = v0;
        *(float4*)&C[base + 64] = v1;
    }
}

// ---------------------------------------------------------------------------
// Parallel STABLE counting-sort CSR with packed (src, dinv_src) slots.
// ---------------------------------------------------------------------------
__global__ __launch_bounds__(256)
void csr_build(const int* __restrict__ ei, const int* __restrict__ cur, int npg,
               int* __restrict__ degS, float* __restrict__ dinvS,
               int* __restrict__ startsS, int2* __restrict__ slots2) {
    __shared__ int cul[EPG];
    __shared__ short dstv[EPG];
    __shared__ unsigned char rnk[EPG];
    __shared__ int h[32][256];
    __shared__ int cnt[256];
    __shared__ int st[256];
    const int g = blockIdx.x;
    const int t = threadIdx.x;
    const int lane = t & 63;
    const int wv = t >> 6;

    for (int i = t; i < 32 * 256; i += 256) ((int*)h)[i] = 0;
    for (int e = t; e < EPG; e += 256) {
        size_t idx = (size_t)g * EPG + e;
        int cu = cur[g * 256 + (ei[idx] - g * 256)];
        int cv = cur[g * 256 + (ei[E_TOT + idx] - g * 256)];
        bool valid = (cu >= 0 && cv >= 0);
        cul[e] = cu;
        dstv[e] = valid ? (short)cv : (short)256;
    }
    __syncthreads();
    for (int c = wv; c < 32; c += 4) {
        int e = c * 64 + lane;
        int d = (int)dstv[e];
        unsigned long long m = ~0ULL;
#pragma unroll
        for (int b = 0; b < 9; ++b) {
            unsigned long long bb = __ballot((d >> b) & 1);
            m &= ((d >> b) & 1) ? bb : ~bb;
        }
        int r = __popcll(m & ((1ULL << lane) - 1ULL));
        rnk[e] = (unsigned char)r;
        if (r == 0 && d < 256) h[c][d] = __popcll(m);
    }
    __syncthreads();
    if (t < npg) {
        int run = 0;
        for (int c = 0; c < 32; ++c) { int v = h[c][t]; h[c][t] = run; run += v; }
        cnt[t] = run;
        degS[g * npg + t] = run + 1;
        dinvS[g * npg + t] = 1.0f / sqrtf((float)(run + 1));
    }
    __syncthreads();
    if (t == 0) {
        int run = 0;
        for (int i = 0; i < npg; ++i) { st[i] = run; run += cnt[i]; }
    }
    __syncthreads();
    if (t < npg) startsS[g * npg + t] = g * EPG + st[t];
    for (int e = t; e < EPG; e += 256) {
        int d = (int)dstv[e];
        if (d < npg) {
            int slot = st[d] + h[e >> 6][d] + (int)rnk[e];
            int cu = cul[e];
            float dv = 1.0f / sqrtf((float)(cnt[cu] + 1));   // == dinvS[src]
            slots2[g * EPG + slot] = make_int2(g * npg + cu, __float_as_int(dv));
        }
    }
}

// ---------------------------------------------------------------------------
// conv + relu + pool score, v2: ONE WAVE PER NODE, float4 per lane.
// (R2-proven: bit-exact, dropped agg from 70.6us out of the top-5.)
// ---------------------------------------------------------------------------
__global__ __launch_bounds__(256)
void agg_score2(const int* __restrict__ degS, const float* __restrict__ dinvS,
                const int* __restrict__ startsS, const int2* __restrict__ slots2,
                const float* __restrict__ HL, float* __restrict__ H2,
                const float* __restrict__ bias, const float* __restrict__ pw,
                float* __restrict__ score, int nbOver8) {
    __shared__ float vrow[4][256];
    const int t = threadIdx.x;
    const int wv = t >> 6;
    const int lane = t & 63;
    const int blk = (blockIdx.x & 7) * nbOver8 + (blockIdx.x >> 3);
    const int node = blk * 4 + wv;
    const int cntE = degS[node] - 1;
    const float degF = (float)(cntE + 1);
    const float dn = dinvS[node];
    const int2* sl = slots2 + startsS[node];
    float ax = 0.f, ay = 0.f, az = 0.f, aw = 0.f;
    int j = 0;
    for (; j + 8 <= cntE; j += 8) {
        int2 s[8];
#pragma unroll
        for (int u = 0; u < 8; ++u) s[u] = sl[j + u];
        float4 hv[8];
#pragma unroll
        for (int u = 0; u < 8; ++u)
            hv[u] = *(const float4*)&HL[(size_t)s[u].x * 256 + 4 * lane];
#pragma unroll
        for (int u = 0; u < 8; ++u) {
            float dv = __int_as_float(s[u].y);
            ax += dv * hv[u].x; ay += dv * hv[u].y;
            az += dv * hv[u].z; aw += dv * hv[u].w;
        }
    }
    for (; j + 4 <= cntE; j += 4) {
        int2 s[4];
#pragma unroll
        for (int u = 0; u < 4; ++u) s[u] = sl[j + u];
        float4 hv[4];
#pragma unroll
        for (int u = 0; u < 4; ++u)
            hv[u] = *(const float4*)&HL[(size_t)s[u].x * 256 + 4 * lane];
#pragma unroll
        for (int u = 0; u < 4; ++u) {
            float dv = __int_as_float(s[u].y);
            ax += dv * hv[u].x; ay += dv * hv[u].y;
            az += dv * hv[u].z; aw += dv * hv[u].w;
        }
    }
    for (; j < cntE; ++j) {
        int2 sv = sl[j];
        float dv = __int_as_float(sv.y);
        float4 hv = *(const float4*)&HL[(size_t)sv.x * 256 + 4 * lane];
        ax += dv * hv.x; ay += dv * hv.y; az += dv * hv.z; aw += dv * hv.w;
    }
    const float4 hn = *(const float4*)&HL[(size_t)node * 256 + 4 * lane];
    const float4 bi = *(const float4*)&bias[4 * lane];
    float4 v;
    v.x = ax * dn + hn.x / degF + bi.x;  v.x = fmaxf(v.x, 0.f);
    v.y = ay * dn + hn.y / degF + bi.y;  v.y = fmaxf(v.y, 0.f);
    v.z = az * dn + hn.z / degF + bi.z;  v.z = fmaxf(v.z, 0.f);
    v.w = aw * dn + hn.w / degF + bi.w;  v.w = fmaxf(v.w, 0.f);
    *(float4*)&H2[(size_t)node * 256 + 4 * lane] = v;
    *(float4*)&vrow[wv][4 * lane] = v;
    // same-wave LDS RAW: compiler inserts the lgkmcnt; no cross-wave sharing.
    float pr = 0.f, s2p = 0.f;
    for (int jj = 0; jj < 4; ++jj) {
        int f = lane + 64 * jj;
        float w = pw[f];
        pr += vrow[wv][f] * w;
        s2p += w * w;
    }
    for (int off = 32; off; off >>= 1) {
        pr += __shfl_down(pr, off, 64);
        s2p += __shfl_down(s2p, off, 64);
    }
    s2p = __shfl(s2p, 0, 64);
    if (lane == 0) score[node] = tanhf(pr / sqrtf(s2p));
}

// ---------------------------------------------------------------------------
__global__ __launch_bounds__(256)
void topk_cur(const float* __restrict__ score, int npg, int k,
              int* __restrict__ kept, int* __restrict__ cur) {
    __shared__ float ss[256];
    __shared__ int si_[256];
    __shared__ int rankOf[256];
    const int g = blockIdx.x;
    const int t = threadIdx.x;
    if (t < npg) { ss[t] = score[g * npg + t]; si_[t] = t; }
    else         { ss[t] = -INFINITY; si_[t] = 0x7FFFFFFF; }
    for (int size = 2; size <= 256; size <<= 1) {
        for (int stride = size >> 1; stride > 0; stride >>= 1) {
            __syncthreads();
            int i = t, j = t ^ stride;
            if (j > i) {
                float a = ss[i], b = ss[j];
                int ia = si_[i], ib = si_[j];
                bool inOrder = (a > b) || (a == b && ia < ib);
                bool desc = ((i & size) == 0);
                if (desc ? !inOrder : inOrder) {
                    ss[i] = b; ss[j] = a; si_[i] = ib; si_[j] = ia;
                }
            }
        }
    }
    __syncthreads();
    rankOf[t] = -1;
    __syncthreads();
    if (t < k) {
        kept[g * k + t] = g * npg + si_[t];
        rankOf[si_[t]] = t;
    }
    __syncthreads();
    {
        int v = g * 256 + t;
        int c = cur[v];
        cur[v] = (c >= 0) ? rankOf[c] : -1;
    }
}

__global__ __launch_bounds__(256)
void pool_gather(const int* __restrict__ kept, const float* __restrict__ score,
                 const float* __restrict__ H2, float* __restrict__ OUT) {
    const int j = blockIdx.x;
    const int t = threadIdx.x;
    const int o = kept[j];
    OUT[(size_t)j * 256 + t] = H2[(size_t)o * 256 + t] * score[o];
}

__global__ __launch_bounds__(256)
void readout(const float* __restrict__ X, int k, float* __restrict__ outacc,
             int first) {
    const int g = blockIdx.x;
    const int t = threadIdx.x;
    const float* base = X + (size_t)g * k * 256 + t;
    float mx = -INFINITY, sm = 0.f;
    for (int n = 0; n < k; ++n) {
        float vv = base[(size_t)n * 256];
        mx = fmaxf(mx, vv);
        sm += vv;
    }
    float mean = sm / (float)k;
    if (first) {
        outacc[g * 512 + t] = mx;
        outacc[g * 512 + 256 + t] = mean;
    } else {
        outacc[g * 512 + t] += mx;
        outacc[g * 512 + 256 + t] += mean;
    }
}

__global__ __launch_bounds__(256)
void mlp_head(const float* __restrict__ outacc,
              const float* __restrict__ l1w, const float* __restrict__ l1b,
              const float* __restrict__ l2w, const float* __restrict__ l2b,
              const float* __restrict__ l3w, const float* __restrict__ l3b,
              float* __restrict__ out) {
    __shared__ float row[512];
    __shared__ float h1[256];
    __shared__ float h2[128];
    const int g = blockIdx.x;
    const int t = threadIdx.x;
    row[t] = outacc[g * 512 + t];
    row[256 + t] = outacc[g * 512 + 256 + t];
    __syncthreads();
    {
        float a = l1b[t];
        for (int j = 0; j < 512; ++j) a += row[j] * l1w[j * 256 + t];
        h1[t] = fmaxf(a, 0.f);
    }
    __syncthreads();
    if (t < 128) {
        float a2 = l2b[t];
        for (int j = 0; j < 256; ++j) a2 += h1[j] * l2w[j * 128 + t];
        h2[t] = fmaxf(a2, 0.f);
    }
    __syncthreads();
    if (t == 0) {
        float l0 = l3b[0], l1 = l3b[1];
        for (int j = 0; j < 128; ++j) {
            float h = h2[j];
            l0 += h * l3w[j * 2 + 0];
            l1 += h * l3w[j * 2 + 1];
        }
        float m = fmaxf(l0, l1);
        float lse = m + logf(expf(l0 - m) + expf(l1 - m));
        out[g * 2 + 0] = l0 - lse;
        out[g * 2 + 1] = l1 - lse;
    }
}

// ============================================================================
// Fallback: proven R15 monolith (used only if ws_size is too small)
// ============================================================================
__global__ __launch_bounds__(256, 1)
void gnn_mono(const float* __restrict__ x, const int* __restrict__ ei,
              const float* __restrict__ gw0, const float* __restrict__ gb0,
              const float* __restrict__ gw1, const float* __restrict__ gb1,
              const float* __restrict__ gw2, const float* __restrict__ gb2,
              const float* __restrict__ pw0, const float* __restrict__ pw1,
              const float* __restrict__ pw2,
              const float* __restrict__ l1w, const float* __restrict__ l1b,
              const float* __restrict__ l2w, const float* __restrict__ l2b,
              const float* __restrict__ l3w, const float* __restrict__ l3b,
              float* __restrict__ out, float* __restrict__ ws) {
    const int g = blockIdx.x;
    const int t = threadIdx.x;
    float* P = ws + (size_t)g * HF * 256;
    float* Q = ws + (size_t)G_GRAPHS * HF * 256 + (size_t)g * HF * 256;
    __shared__ int   eb[EPG];
    __shared__ int   slots[EPG];
    __shared__ int   curID[256];
    __shared__ int   cntL[256];
    __shared__ int   startL[256];
    __shared__ float degF[256];
    __shared__ float dinv[256];
    __shared__ float sa[256];
    __shared__ float ss[256];
    __shared__ int   si_[256];
    __shared__ float scoreV[256];
    __shared__ int   kept[128];
    __shared__ int   rankOf[256];
    __shared__ float row[512];
    for (int e = t; e < EPG; e += 256) {
        size_t idx = (size_t)g * EPG + e;
        eb[e] = ((ei[idx] - g * 256) << 8) | (ei[E_TOT + idx] - g * 256);
    }
    curID[t] = t;
    float accMx = 0.f, accMn = 0.f;
    const float* GW[3] = {gw0, gw1, gw2};
    const float* GB[3] = {gb0, gb1, gb2};
    const float* PW[3] = {pw0, pw1, pw2};
    const int kk[3] = {128, 64, 32};
    int npg = 256;
    __syncthreads();
    for (int s = 0; s < 3; ++s) {
        const int knext = kk[s];
        {
            const float* Wp = GW[s];
            const int K = (s == 0) ? FIN : HF;
            for (int n = 0; n < npg; ++n) {
                if (s == 0) { if (t < FIN) sa[t] = x[(size_t)(g * 256 + n) * FIN + t]; }
                else sa[t] = P[(size_t)n * HF + t];
                __syncthreads();
                float a = 0.f;
                for (int k2 = 0; k2 < K; ++k2) a += sa[k2] * Wp[k2 * HF + t];
                Q[(size_t)n * HF + t] = a;
                __syncthreads();
            }
        }
        cntL[t] = 0;
        __syncthreads();
        for (int e = t; e < EPG; e += 256) {
            int p = eb[e];
            int cu = curID[p >> 8], cv = curID[p & 255];
            if (cu >= 0 && cv >= 0) atomicAdd(&cntL[cv], 1);
        }
        __syncthreads();
        if (t == 0) { int run = 0; for (int i = 0; i < npg; ++i) { startL[i] = run; run += cntL[i]; } }
        __syncthreads();
        if (t < npg) {
            float d = (float)cntL[t] + 1.0f;
            degF[t] = d;
            dinv[t] = 1.0f / sqrtf(d);
            int c = startL[t];
            for (int e = 0; e < EPG; ++e) {
                int p = eb[e];
                int cu = curID[p >> 8], cv = curID[p & 255];
                if (cu >= 0 && cv >= 0 && cv == t) slots[c++] = e;
            }
        }
        __syncthreads();
        {
            const float bb = GB[s][t];
            for (int n = 0; n < npg; ++n) {
                float acc = 0.f;
                const int s0 = startL[n], s1 = s0 + cntL[n];
                for (int j = s0; j < s1; ++j) {
                    int scur = curID[eb[slots[j]] >> 8];
                    acc += dinv[scur] * Q[(size_t)scur * HF + t];
                }
                float v = acc * dinv[n] + Q[(size_t)n * HF + t] / degF[n] + bb;
                P[(size_t)n * HF + t] = fmaxf(v, 0.f);
            }
        }
        __syncthreads();
        {
            const float* pwp = PW[s];
            const int lane = t & 63, wv = t >> 6;
            float s2p = 0.f;
            for (int j = 0; j < 4; ++j) { float w = pwp[lane + 64 * j]; s2p += w * w; }
            for (int off = 32; off; off >>= 1) s2p += __shfl_down(s2p, off, 64);
            s2p = __shfl(s2p, 0, 64);
            const float nw = sqrtf(s2p);
            for (int n = wv; n < npg; n += 4) {
                float pr = 0.f;
                for (int j = 0; j < 4; ++j) { int f = lane + 64 * j; pr += P[(size_t)n * HF + f] * pwp[f]; }
                for (int off = 32; off; off >>= 1) pr += __shfl_down(pr, off, 64);
                if (lane == 0) scoreV[n] = tanhf(pr / nw);
            }
        }
        __syncthreads();
        if (t < npg) { ss[t] = scoreV[t]; si_[t] = t; }
        else         { ss[t] = -INFINITY; si_[t] = 0x7FFFFFFF; }
        for (int size = 2; size <= 256; size <<= 1) {
            for (int stride = size >> 1; stride > 0; stride >>= 1) {
                __syncthreads();
                int i = t, j = t ^ stride;
                if (j > i) {
                    float a = ss[i], b = ss[j];
                    int ia = si_[i], ib = si_[j];
                    bool inOrder = (a > b) || (a == b && ia < ib);
                    bool desc = ((i & size) == 0);
                    if (desc ? !inOrder : inOrder) { ss[i] = b; ss[j] = a; si_[i] = ib; si_[j] = ia; }
                }
            }
        }
        __syncthreads();
        if (t < knext) kept[t] = si_[t];
        __syncthreads();
        {
            float mx = -INFINITY, sm = 0.f;
            for (int n = 0; n < knext; ++n) {
                int o = kept[n];
                float vv = P[(size_t)o * HF + t] * scoreV[o];
                Q[(size_t)n * HF + t] = vv;
                mx = fmaxf(mx, vv);
                sm += vv;
            }
            accMx += mx;
            accMn += sm / (float)knext;
        }
        rankOf[t] = -1;
        __syncthreads();
        if (t < knext) rankOf[kept[t]] = t;
        __syncthreads();
        { int c = curID[t]; curID[t] = (c >= 0) ? rankOf[c] : -1; }
        __syncthreads();
        { float* tmp = P; P = Q; Q = tmp; }
        npg = knext;
    }
    row[t] = accMx;
    row[256 + t] = accMn;
    __syncthreads();
    { float a = l1b[t]; for (int j = 0; j < 512; ++j) a += row[j] * l1w[j * 256 + t]; scoreV[t] = fmaxf(a, 0.f); }
    __syncthreads();
    if (t < 128) { float a2 = l2b[t]; for (int j = 0; j < 256; ++j) a2 += scoreV[j] * l2w[j * 128 + t]; sa[t] = fmaxf(a2, 0.f); }
    __syncthreads();
    if (t == 0) {
        float l0 = l3b[0], l1 = l3b[1];
        for (int j = 0; j < 128; ++j) { float h = sa[j]; l0 += h * l3w[j * 2 + 0]; l1 += h * l3w[j * 2 + 1]; }
        float m = fmaxf(l0, l1);
        float lse = m + logf(expf(l0 - m) + expf(l1 - m));
        out[g * 2 + 0] = l0 - lse;
        out[g * 2 + 1] = l1 - lse;
    }
}

// ============================================================================
extern "C" void kernel_launch(void* const* d_in, const int* in_sizes, int n_in,
                              void* d_out, int out_size, void* d_ws, size_t ws_size,
                              hipStream_t stream) {
    const float* x   = (const float*)d_in[0];
    const int*   ei  = (const int*)d_in[1];
    const float* gw0 = (const float*)d_in[3];
    const float* gb0 = (const float*)d_in[4];
    const float* gw1 = (const float*)d_in[5];
    const float* gb1 = (const float*)d_in[6];
    const float* gw2 = (const float*)d_in[7];
    const float* gb2 = (const float*)d_in[8];
    const float* pw0 = (const float*)d_in[9];
    const float* pw1 = (const float*)d_in[10];
    const float* pw2 = (const float*)d_in[11];
    const float* l1w = (const float*)d_in[12];
    const float* l1b = (const float*)d_in[13];
    const float* l2w = (const float*)d_in[14];
    const float* l2b = (const float*)d_in[15];
    const float* l3w = (const float*)d_in[16];
    const float* l3b = (const float*)d_in[17];
    float* out = (float*)d_out;

    const size_t SLAB = (size_t)65536 * 256;
    char* p = (char*)d_ws;
    float* P      = (float*)p; p += SLAB * 4;
    float* Q      = (float*)p; p += SLAB * 4;
    int*   cur    = (int*)p;   p += (size_t)65536 * 4;
    int*   degS   = (int*)p;   p += (size_t)65536 * 4;
    float* dinvS  = (float*)p; p += (size_t)65536 * 4;
    int*   starts = (int*)p;   p += (size_t)65536 * 4;
    int2*  slots2 = (int2*)p;  p += (size_t)E_TOT * 8;
    float* score  = (float*)p; p += (size_t)65536 * 4;
    int*   kept   = (int*)p;   p += (size_t)32768 * 4;
    float* outacc = (float*)p; p += (size_t)G_GRAPHS * 512 * 4;
    const size_t needed = (size_t)(p - (char*)d_ws);

    if (ws_size < needed) {
        gnn_mono<<<G_GRAPHS, 256, 0, stream>>>(
            x, ei, gw0, gb0, gw1, gb1, gw2, gb2, pw0, pw1, pw2,
            l1w, l1b, l2w, l2b, l3w, l3b, out, (float*)d_ws);
        return;
    }

    init_cur<<<(G_GRAPHS * 256 + 255) / 256, 256, 0, stream>>>(cur);

    const int   npg[3] = {256, 128, 64};
    const int   kk[3]  = {128, 64, 32};
    const int   Ns[3]  = {65536, 32768, 16384};
    const float* GW[3] = {gw0, gw1, gw2};
    const float* GB[3] = {gb0, gb1, gb2};
    const float* PW[3] = {pw0, pw1, pw2};

    float* HLs[3]   = {P, Q, P};
    float* H2s[3]   = {Q, P, Q};
    float* POOLs[3] = {P, Q, P};

    for (int s = 0; s < 3; ++s) {
        const int n = Ns[s];
        const int k = kk[s];
        // 1) GEMM v6: A swizzled-transpose LDS + split-half W LDS
        if (s == 0) {
            gemm_v6<FIN><<<dim3(n / 128, 2), 256, 0, stream>>>(x, GW[s], HLs[s]);
        } else {
            gemm_v6<HF><<<dim3(n / 128, 2), 256, 0, stream>>>(POOLs[s - 1], GW[s], HLs[s]);
        }
        // 2) CSR (parallel stable counting sort, packed slots)
        csr_build<<<G_GRAPHS, 256, 0, stream>>>(ei, cur, npg[s],
                                                degS, dinvS, starts, slots2);
        // 3) conv + score v2: wave-per-node, float4 gathers, no barriers
        agg_score2<<<n / 4, 256, 0, stream>>>(degS, dinvS, starts, slots2,
                                              HLs[s], H2s[s], GB[s], PW[s], score,
                                              n / 32);
        // 4) top-k + cur update
        topk_cur<<<G_GRAPHS, 256, 0, stream>>>(score, npg[s], k, kept, cur);
        // 5) pool
        pool_gather<<<G_GRAPHS * k, 256, 0, stream>>>(kept, score, H2s[s], POOLs[s]);
        // 6) readout
        readout<<<G_GRAPHS, 256, 0, stream>>>(POOLs[s], k, outacc, s == 0 ? 1 : 0);
    }

    mlp_head<<<G_GRAPHS, 256, 0, stream>>>(outacc, l1w, l1b, l2w, l2b, l3w, l3b, out);
}

// Round 4
// 521.863 us; speedup vs baseline: 1.1660x; 1.0180x over previous
//
#include <hip/hip_runtime.h>
#include <hip/hip_bf16.h>
#include <math.h>

#define G_GRAPHS 256
#define EPG 2048
#define E_TOT 524288
#define HF 256
#define FIN 128

// ============================================================================
__global__ void init_cur(int* __restrict__ cur) {
    int i = blockIdx.x * blockDim.x + threadIdx.x;
    if (i < G_GRAPHS * 256) cur[i] = i & 255;
}

// ---------------------------------------------------------------------------
// C[N x 256] = A[N x K] @ W[K x 256], fp32, k-ascending single-accumulator
// chains (bit-exact vs all previous versions).
// v7 = v6's proven conflict-free layouts at HALF the tile for 2x occupancy.
// R3 showed the GEMM was GRID-limited: 128x128 tile gave s1 just 512 blocks
// = 2 blocks/CU (Occupancy 18%, VALUBusy 44%, FMA wall 27us vs measured 70).
//   * 64x128 tile, 4x8/thread, BK=32 -> s1 = 1024 blocks = 4/CU.
//   * A transposed As[kk][row ^ (kq<<3)], stride 68: staging 2-way (free),
//     compute read is ONE ds_read_b128 (rows contiguous), 4-addr broadcast.
//   * W split halves Wa/Wb[32][68]: staging 2-way, reads 2-way + broadcast.
//   * LDS 25.5KB -> 6 blocks/CU resource ceiling; acc=32 VGPR.
// ---------------------------------------------------------------------------
template <int K>
__global__ __launch_bounds__(256, 4)
void gemm_v7(const float* __restrict__ A, const float* __restrict__ W,
             float* __restrict__ C) {
    __shared__ __align__(16) float As[32 * 68];
    __shared__ __align__(16) float Wa[32 * 68];
    __shared__ __align__(16) float Wb[32 * 68];
    const int tid = threadIdx.x;
    const int tx = tid & 15;    // col groups: c0 + tx*4, c0 + 64 + tx*4
    const int ty = tid >> 4;    // rows r0 + ty*4 .. +3
    const int r0 = blockIdx.x * 64;
    const int c0 = blockIdx.y * 128;
    float acc[4][8] = {{0.f}};
    const int l8 = tid >> 3;    // 0..31
    const int kq = tid & 7;     // float4 index along k for A staging
    for (int k0 = 0; k0 < K; k0 += 32) {
        // stage A: 64 rows x 32 kk, transposed + kq-XOR swizzle
#pragma unroll
        for (int it = 0; it < 2; ++it) {
            int row = it * 32 + l8;
            float4 v = *(const float4*)&A[(size_t)(r0 + row) * K + k0 + 4 * kq];
            int rs = row ^ (kq << 3);
            As[(4 * kq + 0) * 68 + rs] = v.x;
            As[(4 * kq + 1) * 68 + rs] = v.y;
            As[(4 * kq + 2) * 68 + rs] = v.z;
            As[(4 * kq + 3) * 68 + rs] = v.w;
        }
        // stage W: 32 kk x 128 cols -> split halves (stride 68)
#pragma unroll
        for (int it = 0; it < 4; ++it) {
            int idx = it * 256 + tid;      // 0..1023
            int kk = idx >> 5;             // 0..31
            int c = idx & 31;              // float4 col index
            float4 v = *(const float4*)&W[(size_t)(k0 + kk) * 256 + c0 + 4 * c];
            if (c < 16) *(float4*)&Wa[kk * 68 + 4 * c] = v;
            else        *(float4*)&Wb[kk * 68 + 4 * (c - 16)] = v;
        }
        __syncthreads();
#pragma unroll 4
        for (int kk = 0; kk < 32; ++kk) {
            const int g = (ty * 4) ^ ((kk >> 2) << 3);
            const float4 a0 = *(const float4*)&As[kk * 68 + g];
            const float4 w0 = *(const float4*)&Wa[kk * 68 + tx * 4];
            const float4 w1 = *(const float4*)&Wb[kk * 68 + tx * 4];
            float av[4] = {a0.x, a0.y, a0.z, a0.w};
            float wv_[8] = {w0.x, w0.y, w0.z, w0.w, w1.x, w1.y, w1.z, w1.w};
#pragma unroll
            for (int i = 0; i < 4; ++i)
#pragma unroll
                for (int j = 0; j < 8; ++j)
                    acc[i][j] += av[i] * wv_[j];
        }
        __syncthreads();
    }
#pragma unroll
    for (int i = 0; i < 4; ++i) {
        float4 v0 = make_float4(acc[i][0], acc[i][1], acc[i][2], acc[i][3]);
        float4 v1 = make_float4(acc[i][4], acc[i][5], acc[i][6], acc[i][7]);
        size_t base = (size_t)(r0 + ty * 4 + i) * 256 + c0 + tx * 4;
        *(float4*)&C[base] = v0;
        *(float4*)&C[base + 64] = v1;
    }
}

// ---------------------------------------------------------------------------
// Parallel STABLE counting-sort CSR with packed (src, dinv_src) slots.
// ---------------------------------------------------------------------------
__global__ __launch_bounds__(256)
void csr_build(const int* __restrict__ ei, const int* __restrict__ cur, int npg,
               int* __restrict__ degS, float* __restrict__ dinvS,
               int* __restrict__ startsS, int2* __restrict__ slots2) {
    __shared__ int cul[EPG];
    __shared__ short dstv[EPG];
    __shared__ unsigned char rnk[EPG];
    __shared__ int h[32][256];
    __shared__ int cnt[256];
    __shared__ int st[256];
    const int g = blockIdx.x;
    const int t = threadIdx.x;
    const int lane = t & 63;
    const int wv = t >> 6;

    for (int i = t; i < 32 * 256; i += 256) ((int*)h)[i] = 0;
    for (int e = t; e < EPG; e += 256) {
        size_t idx = (size_t)g * EPG + e;
        int cu = cur[g * 256 + (ei[idx] - g * 256)];
        int cv = cur[g * 256 + (ei[E_TOT + idx] - g * 256)];
        bool valid = (cu >= 0 && cv >= 0);
        cul[e] = cu;
        dstv[e] = valid ? (short)cv : (short)256;
    }
    __syncthreads();
    for (int c = wv; c < 32; c += 4) {
        int e = c * 64 + lane;
        int d = (int)dstv[e];
        unsigned long long m = ~0ULL;
#pragma unroll
        for (int b = 0; b < 9; ++b) {
            unsigned long long bb = __ballot((d >> b) & 1);
            m &= ((d >> b) & 1) ? bb : ~bb;
        }
        int r = __popcll(m & ((1ULL << lane) - 1ULL));
        rnk[e] = (unsigned char)r;
        if (r == 0 && d < 256) h[c][d] = __popcll(m);
    }
    __syncthreads();
    if (t < npg) {
        int run = 0;
        for (int c = 0; c < 32; ++c) { int v = h[c][t]; h[c][t] = run; run += v; }
        cnt[t] = run;
        degS[g * npg + t] = run + 1;
        dinvS[g * npg + t] = 1.0f / sqrtf((float)(run + 1));
    }
    __syncthreads();
    if (t == 0) {
        int run = 0;
        for (int i = 0; i < npg; ++i) { st[i] = run; run += cnt[i]; }
    }
    __syncthreads();
    if (t < npg) startsS[g * npg + t] = g * EPG + st[t];
    for (int e = t; e < EPG; e += 256) {
        int d = (int)dstv[e];
        if (d < npg) {
            int slot = st[d] + h[e >> 6][d] + (int)rnk[e];
            int cu = cul[e];
            float dv = 1.0f / sqrtf((float)(cnt[cu] + 1));   // == dinvS[src]
            slots2[g * EPG + slot] = make_int2(g * npg + cu, __float_as_int(dv));
        }
    }
}

// ---------------------------------------------------------------------------
// conv + relu + pool score, v2: ONE WAVE PER NODE, float4 per lane.
// (R2-proven: bit-exact, dropped agg from 70.6us out of the top-5.)
// ---------------------------------------------------------------------------
__global__ __launch_bounds__(256)
void agg_score2(const int* __restrict__ degS, const float* __restrict__ dinvS,
                const int* __restrict__ startsS, const int2* __restrict__ slots2,
                const float* __restrict__ HL, float* __restrict__ H2,
                const float* __restrict__ bias, const float* __restrict__ pw,
                float* __restrict__ score, int nbOver8) {
    __shared__ float vrow[4][256];
    const int t = threadIdx.x;
    const int wv = t >> 6;
    const int lane = t & 63;
    const int blk = (blockIdx.x & 7) * nbOver8 + (blockIdx.x >> 3);
    const int node = blk * 4 + wv;
    const int cntE = degS[node] - 1;
    const float degF = (float)(cntE + 1);
    const float dn = dinvS[node];
    const int2* sl = slots2 + startsS[node];
    float ax = 0.f, ay = 0.f, az = 0.f, aw = 0.f;
    int j = 0;
    for (; j + 8 <= cntE; j += 8) {
        int2 s[8];
#pragma unroll
        for (int u = 0; u < 8; ++u) s[u] = sl[j + u];
        float4 hv[8];
#pragma unroll
        for (int u = 0; u < 8; ++u)
            hv[u] = *(const float4*)&HL[(size_t)s[u].x * 256 + 4 * lane];
#pragma unroll
        for (int u = 0; u < 8; ++u) {
            float dv = __int_as_float(s[u].y);
            ax += dv * hv[u].x; ay += dv * hv[u].y;
            az += dv * hv[u].z; aw += dv * hv[u].w;
        }
    }
    for (; j + 4 <= cntE; j += 4) {
        int2 s[4];
#pragma unroll
        for (int u = 0; u < 4; ++u) s[u] = sl[j + u];
        float4 hv[4];
#pragma unroll
        for (int u = 0; u < 4; ++u)
            hv[u] = *(const float4*)&HL[(size_t)s[u].x * 256 + 4 * lane];
#pragma unroll
        for (int u = 0; u < 4; ++u) {
            float dv = __int_as_float(s[u].y);
            ax += dv * hv[u].x; ay += dv * hv[u].y;
            az += dv * hv[u].z; aw += dv * hv[u].w;
        }
    }
    for (; j < cntE; ++j) {
        int2 sv = sl[j];
        float dv = __int_as_float(sv.y);
        float4 hv = *(const float4*)&HL[(size_t)sv.x * 256 + 4 * lane];
        ax += dv * hv.x; ay += dv * hv.y; az += dv * hv.z; aw += dv * hv.w;
    }
    const float4 hn = *(const float4*)&HL[(size_t)node * 256 + 4 * lane];
    const float4 bi = *(const float4*)&bias[4 * lane];
    float4 v;
    v.x = ax * dn + hn.x / degF + bi.x;  v.x = fmaxf(v.x, 0.f);
    v.y = ay * dn + hn.y / degF + bi.y;  v.y = fmaxf(v.y, 0.f);
    v.z = az * dn + hn.z / degF + bi.z;  v.z = fmaxf(v.z, 0.f);
    v.w = aw * dn + hn.w / degF + bi.w;  v.w = fmaxf(v.w, 0.f);
    *(float4*)&H2[(size_t)node * 256 + 4 * lane] = v;
    *(float4*)&vrow[wv][4 * lane] = v;
    // same-wave LDS RAW: compiler inserts the lgkmcnt; no cross-wave sharing.
    float pr = 0.f, s2p = 0.f;
    for (int jj = 0; jj < 4; ++jj) {
        int f = lane + 64 * jj;
        float w = pw[f];
        pr += vrow[wv][f] * w;
        s2p += w * w;
    }
    for (int off = 32; off; off >>= 1) {
        pr += __shfl_down(pr, off, 64);
        s2p += __shfl_down(s2p, off, 64);
    }
    s2p = __shfl(s2p, 0, 64);
    if (lane == 0) score[node] = tanhf(pr / sqrtf(s2p));
}

// ---------------------------------------------------------------------------
__global__ __launch_bounds__(256)
void topk_cur(const float* __restrict__ score, int npg, int k,
              int* __restrict__ kept, int* __restrict__ cur) {
    __shared__ float ss[256];
    __shared__ int si_[256];
    __shared__ int rankOf[256];
    const int g = blockIdx.x;
    const int t = threadIdx.x;
    if (t < npg) { ss[t] = score[g * npg + t]; si_[t] = t; }
    else         { ss[t] = -INFINITY; si_[t] = 0x7FFFFFFF; }
    for (int size = 2; size <= 256; size <<= 1) {
        for (int stride = size >> 1; stride > 0; stride >>= 1) {
            __syncthreads();
            int i = t, j = t ^ stride;
            if (j > i) {
                float a = ss[i], b = ss[j];
                int ia = si_[i], ib = si_[j];
                bool inOrder = (a > b) || (a == b && ia < ib);
                bool desc = ((i & size) == 0);
                if (desc ? !inOrder : inOrder) {
                    ss[i] = b; ss[j] = a; si_[i] = ib; si_[j] = ia;
                }
            }
        }
    }
    __syncthreads();
    rankOf[t] = -1;
    __syncthreads();
    if (t < k) {
        kept[g * k + t] = g * npg + si_[t];
        rankOf[si_[t]] = t;
    }
    __syncthreads();
    {
        int v = g * 256 + t;
        int c = cur[v];
        cur[v] = (c >= 0) ? rankOf[c] : -1;
    }
}

__global__ __launch_bounds__(256)
void pool_gather(const int* __restrict__ kept, const float* __restrict__ score,
                 const float* __restrict__ H2, float* __restrict__ OUT) {
    const int j = blockIdx.x;
    const int t = threadIdx.x;
    const int o = kept[j];
    OUT[(size_t)j * 256 + t] = H2[(size_t)o * 256 + t] * score[o];
}

__global__ __launch_bounds__(256)
void readout(const float* __restrict__ X, int k, float* __restrict__ outacc,
             int first) {
    const int g = blockIdx.x;
    const int t = threadIdx.x;
    const float* base = X + (size_t)g * k * 256 + t;
    float mx = -INFINITY, sm = 0.f;
    for (int n = 0; n < k; ++n) {
        float vv = base[(size_t)n * 256];
        mx = fmaxf(mx, vv);
        sm += vv;
    }
    float mean = sm / (float)k;
    if (first) {
        outacc[g * 512 + t] = mx;
        outacc[g * 512 + 256 + t] = mean;
    } else {
        outacc[g * 512 + t] += mx;
        outacc[g * 512 + 256 + t] += mean;
    }
}

__global__ __launch_bounds__(256)
void mlp_head(const float* __restrict__ outacc,
              const float* __restrict__ l1w, const float* __restrict__ l1b,
              const float* __restrict__ l2w, const float* __restrict__ l2b,
              const float* __restrict__ l3w, const float* __restrict__ l3b,
              float* __restrict__ out) {
    __shared__ float row[512];
    __shared__ float h1[256];
    __shared__ float h2[128];
    const int g = blockIdx.x;
    const int t = threadIdx.x;
    row[t] = outacc[g * 512 + t];
    row[256 + t] = outacc[g * 512 + 256 + t];
    __syncthreads();
    {
        float a = l1b[t];
        for (int j = 0; j < 512; ++j) a += row[j] * l1w[j * 256 + t];
        h1[t] = fmaxf(a, 0.f);
    }
    __syncthreads();
    if (t < 128) {
        float a2 = l2b[t];
        for (int j = 0; j < 256; ++j) a2 += h1[j] * l2w[j * 128 + t];
        h2[t] = fmaxf(a2, 0.f);
    }
    __syncthreads();
    if (t == 0) {
        float l0 = l3b[0], l1 = l3b[1];
        for (int j = 0; j < 128; ++j) {
            float h = h2[j];
            l0 += h * l3w[j * 2 + 0];
            l1 += h * l3w[j * 2 + 1];
        }
        float m = fmaxf(l0, l1);
        float lse = m + logf(expf(l0 - m) + expf(l1 - m));
        out[g * 2 + 0] = l0 - lse;
        out[g * 2 + 1] = l1 - lse;
    }
}

// ============================================================================
// Fallback: proven R15 monolith (used only if ws_size is too small)
// ============================================================================
__global__ __launch_bounds__(256, 1)
void gnn_mono(const float* __restrict__ x, const int* __restrict__ ei,
              const float* __restrict__ gw0, const float* __restrict__ gb0,
              const float* __restrict__ gw1, const float* __restrict__ gb1,
              const float* __restrict__ gw2, const float* __restrict__ gb2,
              const float* __restrict__ pw0, const float* __restrict__ pw1,
              const float* __restrict__ pw2,
              const float* __restrict__ l1w, const float* __restrict__ l1b,
              const float* __restrict__ l2w, const float* __restrict__ l2b,
              const float* __restrict__ l3w, const float* __restrict__ l3b,
              float* __restrict__ out, float* __restrict__ ws) {
    const int g = blockIdx.x;
    const int t = threadIdx.x;
    float* P = ws + (size_t)g * HF * 256;
    float* Q = ws + (size_t)G_GRAPHS * HF * 256 + (size_t)g * HF * 256;
    __shared__ int   eb[EPG];
    __shared__ int   slots[EPG];
    __shared__ int   curID[256];
    __shared__ int   cntL[256];
    __shared__ int   startL[256];
    __shared__ float degF[256];
    __shared__ float dinv[256];
    __shared__ float sa[256];
    __shared__ float ss[256];
    __shared__ int   si_[256];
    __shared__ float scoreV[256];
    __shared__ int   kept[128];
    __shared__ int   rankOf[256];
    __shared__ float row[512];
    for (int e = t; e < EPG; e += 256) {
        size_t idx = (size_t)g * EPG + e;
        eb[e] = ((ei[idx] - g * 256) << 8) | (ei[E_TOT + idx] - g * 256);
    }
    curID[t] = t;
    float accMx = 0.f, accMn = 0.f;
    const float* GW[3] = {gw0, gw1, gw2};
    const float* GB[3] = {gb0, gb1, gb2};
    const float* PW[3] = {pw0, pw1, pw2};
    const int kk[3] = {128, 64, 32};
    int npg = 256;
    __syncthreads();
    for (int s = 0; s < 3; ++s) {
        const int knext = kk[s];
        {
            const float* Wp = GW[s];
            const int K = (s == 0) ? FIN : HF;
            for (int n = 0; n < npg; ++n) {
                if (s == 0) { if (t < FIN) sa[t] = x[(size_t)(g * 256 + n) * FIN + t]; }
                else sa[t] = P[(size_t)n * HF + t];
                __syncthreads();
                float a = 0.f;
                for (int k2 = 0; k2 < K; ++k2) a += sa[k2] * Wp[k2 * HF + t];
                Q[(size_t)n * HF + t] = a;
                __syncthreads();
            }
        }
        cntL[t] = 0;
        __syncthreads();
        for (int e = t; e < EPG; e += 256) {
            int p = eb[e];
            int cu = curID[p >> 8], cv = curID[p & 255];
            if (cu >= 0 && cv >= 0) atomicAdd(&cntL[cv], 1);
        }
        __syncthreads();
        if (t == 0) { int run = 0; for (int i = 0; i < npg; ++i) { startL[i] = run; run += cntL[i]; } }
        __syncthreads();
        if (t < npg) {
            float d = (float)cntL[t] + 1.0f;
            degF[t] = d;
            dinv[t] = 1.0f / sqrtf(d);
            int c = startL[t];
            for (int e = 0; e < EPG; ++e) {
                int p = eb[e];
                int cu = curID[p >> 8], cv = curID[p & 255];
                if (cu >= 0 && cv >= 0 && cv == t) slots[c++] = e;
            }
        }
        __syncthreads();
        {
            const float bb = GB[s][t];
            for (int n = 0; n < npg; ++n) {
                float acc = 0.f;
                const int s0 = startL[n], s1 = s0 + cntL[n];
                for (int j = s0; j < s1; ++j) {
                    int scur = curID[eb[slots[j]] >> 8];
                    acc += dinv[scur] * Q[(size_t)scur * HF + t];
                }
                float v = acc * dinv[n] + Q[(size_t)n * HF + t] / degF[n] + bb;
                P[(size_t)n * HF + t] = fmaxf(v, 0.f);
            }
        }
        __syncthreads();
        {
            const float* pwp = PW[s];
            const int lane = t & 63, wv = t >> 6;
            float s2p = 0.f;
            for (int j = 0; j < 4; ++j) { float w = pwp[lane + 64 * j]; s2p += w * w; }
            for (int off = 32; off; off >>= 1) s2p += __shfl_down(s2p, off, 64);
            s2p = __shfl(s2p, 0, 64);
            const float nw = sqrtf(s2p);
            for (int n = wv; n < npg; n += 4) {
                float pr = 0.f;
                for (int j = 0; j < 4; ++j) { int f = lane + 64 * j; pr += P[(size_t)n * HF + f] * pwp[f]; }
                for (int off = 32; off; off >>= 1) pr += __shfl_down(pr, off, 64);
                if (lane == 0) scoreV[n] = tanhf(pr / nw);
            }
        }
        __syncthreads();
        if (t < npg) { ss[t] = scoreV[t]; si_[t] = t; }
        else         { ss[t] = -INFINITY; si_[t] = 0x7FFFFFFF; }
        for (int size = 2; size <= 256; size <<= 1) {
            for (int stride = size >> 1; stride > 0; stride >>= 1) {
                __syncthreads();
                int i = t, j = t ^ stride;
                if (j > i) {
                    float a = ss[i], b = ss[j];
                    int ia = si_[i], ib = si_[j];
                    bool inOrder = (a > b) || (a == b && ia < ib);
                    bool desc = ((i & size) == 0);
                    if (desc ? !inOrder : inOrder) { ss[i] = b; ss[j] = a; si_[i] = ib; si_[j] = ia; }
                }
            }
        }
        __syncthreads();
        if (t < knext) kept[t] = si_[t];
        __syncthreads();
        {
            float mx = -INFINITY, sm = 0.f;
            for (int n = 0; n < knext; ++n) {
                int o = kept[n];
                float vv = P[(size_t)o * HF + t] * scoreV[o];
                Q[(size_t)n * HF + t] = vv;
                mx = fmaxf(mx, vv);
                sm += vv;
            }
            accMx += mx;
            accMn += sm / (float)knext;
        }
        rankOf[t] = -1;
        __syncthreads();
        if (t < knext) rankOf[kept[t]] = t;
        __syncthreads();
        { int c = curID[t]; curID[t] = (c >= 0) ? rankOf[c] : -1; }
        __syncthreads();
        { float* tmp = P; P = Q; Q = tmp; }
        npg = knext;
    }
    row[t] = accMx;
    row[256 + t] = accMn;
    __syncthreads();
    { float a = l1b[t]; for (int j = 0; j < 512; ++j) a += row[j] * l1w[j * 256 + t]; scoreV[t] = fmaxf(a, 0.f); }
    __syncthreads();
    if (t < 128) { float a2 = l2b[t]; for (int j = 0; j < 256; ++j) a2 += scoreV[j] * l2w[j * 128 + t]; sa[t] = fmaxf(a2, 0.f); }
    __syncthreads();
    if (t == 0) {
        float l0 = l3b[0], l1 = l3b[1];
        for (int j = 0; j < 128; ++j) { float h = sa[j]; l0 += h * l3w[j * 2 + 0]; l1 += h * l3w[j * 2 + 1]; }
        float m = fmaxf(l0, l1);
        float lse = m + logf(expf(l0 - m) + expf(l1 - m));
        out[g * 2 + 0] = l0 - lse;
        out[g * 2 + 1] = l1 - lse;
    }
}

// ============================================================================
extern "C" void kernel_launch(void* const* d_in, const int* in_sizes, int n_in,
                              void* d_out, int out_size, void* d_ws, size_t ws_size,
                              hipStream_t stream) {
    const float* x   = (const float*)d_in[0];
    const int*   ei  = (const int*)d_in[1];
    const float* gw0 = (const float*)d_in[3];
    const float* gb0 = (const float*)d_in[4];
    const float* gw1 = (const float*)d_in[5];
    const float* gb1 = (const float*)d_in[6];
    const float* gw2 = (const float*)d_in[7];
    const float* gb2 = (const float*)d_in[8];
    const float* pw0 = (const float*)d_in[9];
    const float* pw1 = (const float*)d_in[10];
    const float* pw2 = (const float*)d_in[11];
    const float* l1w = (const float*)d_in[12];
    const float* l1b = (const float*)d_in[13];
    const float* l2w = (const float*)d_in[14];
    const float* l2b = (const float*)d_in[15];
    const float* l3w = (const float*)d_in[16];
    const float* l3b = (const float*)d_in[17];
    float* out = (float*)d_out;

    const size_t SLAB = (size_t)65536 * 256;
    char* p = (char*)d_ws;
    float* P      = (float*)p; p += SLAB * 4;
    float* Q      = (float*)p; p += SLAB * 4;
    int*   cur    = (int*)p;   p += (size_t)65536 * 4;
    int*   degS   = (int*)p;   p += (size_t)65536 * 4;
    float* dinvS  = (float*)p; p += (size_t)65536 * 4;
    int*   starts = (int*)p;   p += (size_t)65536 * 4;
    int2*  slots2 = (int2*)p;  p += (size_t)E_TOT * 8;
    float* score  = (float*)p; p += (size_t)65536 * 4;
    int*   kept   = (int*)p;   p += (size_t)32768 * 4;
    float* outacc = (float*)p; p += (size_t)G_GRAPHS * 512 * 4;
    const size_t needed = (size_t)(p - (char*)d_ws);

    if (ws_size < needed) {
        gnn_mono<<<G_GRAPHS, 256, 0, stream>>>(
            x, ei, gw0, gb0, gw1, gb1, gw2, gb2, pw0, pw1, pw2,
            l1w, l1b, l2w, l2b, l3w, l3b, out, (float*)d_ws);
        return;
    }

    init_cur<<<(G_GRAPHS * 256 + 255) / 256, 256, 0, stream>>>(cur);

    const int   npg[3] = {256, 128, 64};
    const int   kk[3]  = {128, 64, 32};
    const int   Ns[3]  = {65536, 32768, 16384};
    const float* GW[3] = {gw0, gw1, gw2};
    const float* GB[3] = {gb0, gb1, gb2};
    const float* PW[3] = {pw0, pw1, pw2};

    float* HLs[3]   = {P, Q, P};
    float* H2s[3]   = {Q, P, Q};
    float* POOLs[3] = {P, Q, P};

    for (int s = 0; s < 3; ++s) {
        const int n = Ns[s];
        const int k = kk[s];
        // 1) GEMM v7: 64x128 tile (2x blocks vs v6), proven LDS layouts
        if (s == 0) {
            gemm_v7<FIN><<<dim3(n / 64, 2), 256, 0, stream>>>(x, GW[s], HLs[s]);
        } else {
            gemm_v7<HF><<<dim3(n / 64, 2), 256, 0, stream>>>(POOLs[s - 1], GW[s], HLs[s]);
        }
        // 2) CSR (parallel stable counting sort, packed slots)
        csr_build<<<G_GRAPHS, 256, 0, stream>>>(ei, cur, npg[s],
                                                degS, dinvS, starts, slots2);
        // 3) conv + score v2: wave-per-node, float4 gathers, no barriers
        agg_score2<<<n / 4, 256, 0, stream>>>(degS, dinvS, starts, slots2,
                                              HLs[s], H2s[s], GB[s], PW[s], score,
                                              n / 32);
        // 4) top-k + cur update
        topk_cur<<<G_GRAPHS, 256, 0, stream>>>(score, npg[s], k, kept, cur);
        // 5) pool
        pool_gather<<<G_GRAPHS * k, 256, 0, stream>>>(kept, score, H2s[s], POOLs[s]);
        // 6) readout
        readout<<<G_GRAPHS, 256, 0, stream>>>(POOLs[s], k, outacc, s == 0 ? 1 : 0);
    }

    mlp_head<<<G_GRAPHS, 256, 0, stream>>>(outacc, l1w, l1b, l2w, l2b, l3w, l3b, out);
}

// Round 5
// 456.272 us; speedup vs baseline: 1.3336x; 1.1438x over previous
//
#include <hip/hip_runtime.h>
#include <hip/hip_bf16.h>
#include <math.h>

#define G_GRAPHS 256
#define EPG 2048
#define E_TOT 524288
#define HF 256
#define FIN 128

// ============================================================================
__global__ void init_cur(int* __restrict__ cur) {
    int i = blockIdx.x * blockDim.x + threadIdx.x;
    if (i < G_GRAPHS * 256) cur[i] = i & 255;
}

// ---------------------------------------------------------------------------
// C[N x 256] = A[N x K] @ W[K x 256], fp32, k-ascending single-accumulator
// chains (bit-exact vs all previous versions).
// v8 = v7 (64x128 tile, 4x8/thread, BK=32, proven conflict-free layouts)
//      + async-STAGE split: issue next tile's global loads into registers
//      BEFORE the compute loop (HBM/L2 latency hides under 2048cy of FMA),
//      then barrier -> ds_write -> barrier. R4 showed ~30us/dispatch of
//      stage-phase exposure (VALUBusy 52%, FMA wall 27us vs measured 63.5).
//      Single LDS buffer (25.5KB) keeps 4-6 blocks/CU occupancy.
// ---------------------------------------------------------------------------
template <int K>
__global__ __launch_bounds__(256, 4)
void gemm_v8(const float* __restrict__ A, const float* __restrict__ W,
             float* __restrict__ C) {
    __shared__ __align__(16) float As[32 * 68];
    __shared__ __align__(16) float Wa[32 * 68];
    __shared__ __align__(16) float Wb[32 * 68];
    const int tid = threadIdx.x;
    const int tx = tid & 15;    // col groups: c0 + tx*4, c0 + 64 + tx*4
    const int ty = tid >> 4;    // rows r0 + ty*4 .. +3
    const int r0 = blockIdx.x * 64;
    const int c0 = blockIdx.y * 128;
    const int l8 = tid >> 3;    // 0..31 (A staging row-within-slab)
    const int kq = tid & 7;     // A staging float4 index along k
    const int wkk = tid >> 5;   // 0..7  (W staging kk base)
    const int wc = tid & 31;    // W staging float4 col index
    float acc[4][8] = {{0.f}};
    float4 va0, va1, vw0, vw1, vw2, vw3;

    auto load_regs = [&](int k0) {
        va0 = *(const float4*)&A[(size_t)(r0 + l8) * K + k0 + 4 * kq];
        va1 = *(const float4*)&A[(size_t)(r0 + 32 + l8) * K + k0 + 4 * kq];
        vw0 = *(const float4*)&W[(size_t)(k0 + 0  + wkk) * 256 + c0 + 4 * wc];
        vw1 = *(const float4*)&W[(size_t)(k0 + 8  + wkk) * 256 + c0 + 4 * wc];
        vw2 = *(const float4*)&W[(size_t)(k0 + 16 + wkk) * 256 + c0 + 4 * wc];
        vw3 = *(const float4*)&W[(size_t)(k0 + 24 + wkk) * 256 + c0 + 4 * wc];
    };
    auto write_stage = [&]() {
        // A transposed + kq-XOR swizzle (staging 2-way free, reads broadcast)
        {
            int rs = l8 ^ (kq << 3);
            As[(4 * kq + 0) * 68 + rs] = va0.x;
            As[(4 * kq + 1) * 68 + rs] = va0.y;
            As[(4 * kq + 2) * 68 + rs] = va0.z;
            As[(4 * kq + 3) * 68 + rs] = va0.w;
        }
        {
            int rs = (32 + l8) ^ (kq << 3);
            As[(4 * kq + 0) * 68 + rs] = va1.x;
            As[(4 * kq + 1) * 68 + rs] = va1.y;
            As[(4 * kq + 2) * 68 + rs] = va1.z;
            As[(4 * kq + 3) * 68 + rs] = va1.w;
        }
        // W split halves (stride 68): staging 2-way, reads 2-way + broadcast
        if (wc < 16) {
            *(float4*)&Wa[(0  + wkk) * 68 + 4 * wc] = vw0;
            *(float4*)&Wa[(8  + wkk) * 68 + 4 * wc] = vw1;
            *(float4*)&Wa[(16 + wkk) * 68 + 4 * wc] = vw2;
            *(float4*)&Wa[(24 + wkk) * 68 + 4 * wc] = vw3;
        } else {
            *(float4*)&Wb[(0  + wkk) * 68 + 4 * (wc - 16)] = vw0;
            *(float4*)&Wb[(8  + wkk) * 68 + 4 * (wc - 16)] = vw1;
            *(float4*)&Wb[(16 + wkk) * 68 + 4 * (wc - 16)] = vw2;
            *(float4*)&Wb[(24 + wkk) * 68 + 4 * (wc - 16)] = vw3;
        }
    };
    auto compute = [&]() {
#pragma unroll 4
        for (int kk = 0; kk < 32; ++kk) {
            const int g = (ty * 4) ^ ((kk >> 2) << 3);
            const float4 a0 = *(const float4*)&As[kk * 68 + g];
            const float4 w0 = *(const float4*)&Wa[kk * 68 + tx * 4];
            const float4 w1 = *(const float4*)&Wb[kk * 68 + tx * 4];
            float av[4] = {a0.x, a0.y, a0.z, a0.w};
            float wv_[8] = {w0.x, w0.y, w0.z, w0.w, w1.x, w1.y, w1.z, w1.w};
#pragma unroll
            for (int i = 0; i < 4; ++i)
#pragma unroll
                for (int j = 0; j < 8; ++j)
                    acc[i][j] += av[i] * wv_[j];
        }
    };

    load_regs(0);
    write_stage();
    __syncthreads();
    for (int k0 = 0; k0 < K - 32; k0 += 32) {
        load_regs(k0 + 32);   // issue early: in flight under compute
        compute();
        __syncthreads();      // all waves done reading this tile
        write_stage();        // vmcnt wait folded here (loads long returned)
        __syncthreads();
    }
    compute();                // last tile

#pragma unroll
    for (int i = 0; i < 4; ++i) {
        float4 v0 = make_float4(acc[i][0], acc[i][1], acc[i][2], acc[i][3]);
        float4 v1 = make_float4(acc[i][4], acc[i][5], acc[i][6], acc[i][7]);
        size_t base = (size_t)(r0 + ty * 4 + i) * 256 + c0 + tx * 4;
        *(float4*)&C[base] = v0;
        *(float4*)&C[base + 64] = v1;
    }
}

// ---------------------------------------------------------------------------
// Parallel STABLE counting-sort CSR with packed (src, dinv_src) slots.
// ---------------------------------------------------------------------------
__global__ __launch_bounds__(256)
void csr_build(const int* __restrict__ ei, const int* __restrict__ cur, int npg,
               int* __restrict__ degS, float* __restrict__ dinvS,
               int* __restrict__ startsS, int2* __restrict__ slots2) {
    __shared__ int cul[EPG];
    __shared__ short dstv[EPG];
    __shared__ unsigned char rnk[EPG];
    __shared__ int h[32][256];
    __shared__ int cnt[256];
    __shared__ int st[256];
    const int g = blockIdx.x;
    const int t = threadIdx.x;
    const int lane = t & 63;
    const int wv = t >> 6;

    for (int i = t; i < 32 * 256; i += 256) ((int*)h)[i] = 0;
    for (int e = t; e < EPG; e += 256) {
        size_t idx = (size_t)g * EPG + e;
        int cu = cur[g * 256 + (ei[idx] - g * 256)];
        int cv = cur[g * 256 + (ei[E_TOT + idx] - g * 256)];
        bool valid = (cu >= 0 && cv >= 0);
        cul[e] = cu;
        dstv[e] = valid ? (short)cv : (short)256;
    }
    __syncthreads();
    for (int c = wv; c < 32; c += 4) {
        int e = c * 64 + lane;
        int d = (int)dstv[e];
        unsigned long long m = ~0ULL;
#pragma unroll
        for (int b = 0; b < 9; ++b) {
            unsigned long long bb = __ballot((d >> b) & 1);
            m &= ((d >> b) & 1) ? bb : ~bb;
        }
        int r = __popcll(m & ((1ULL << lane) - 1ULL));
        rnk[e] = (unsigned char)r;
        if (r == 0 && d < 256) h[c][d] = __popcll(m);
    }
    __syncthreads();
    if (t < npg) {
        int run = 0;
        for (int c = 0; c < 32; ++c) { int v = h[c][t]; h[c][t] = run; run += v; }
        cnt[t] = run;
        degS[g * npg + t] = run + 1;
        dinvS[g * npg + t] = 1.0f / sqrtf((float)(run + 1));
    }
    __syncthreads();
    if (t == 0) {
        int run = 0;
        for (int i = 0; i < npg; ++i) { st[i] = run; run += cnt[i]; }
    }
    __syncthreads();
    if (t < npg) startsS[g * npg + t] = g * EPG + st[t];
    for (int e = t; e < EPG; e += 256) {
        int d = (int)dstv[e];
        if (d < npg) {
            int slot = st[d] + h[e >> 6][d] + (int)rnk[e];
            int cu = cul[e];
            float dv = 1.0f / sqrtf((float)(cnt[cu] + 1));   // == dinvS[src]
            slots2[g * EPG + slot] = make_int2(g * npg + cu, __float_as_int(dv));
        }
    }
}

// ---------------------------------------------------------------------------
// conv + relu + pool score, v2: ONE WAVE PER NODE, float4 per lane.
// (R2-proven: bit-exact, dropped agg from 70.6us out of the top-5.)
// ---------------------------------------------------------------------------
__global__ __launch_bounds__(256)
void agg_score2(const int* __restrict__ degS, const float* __restrict__ dinvS,
                const int* __restrict__ startsS, const int2* __restrict__ slots2,
                const float* __restrict__ HL, float* __restrict__ H2,
                const float* __restrict__ bias, const float* __restrict__ pw,
                float* __restrict__ score, int nbOver8) {
    __shared__ float vrow[4][256];
    const int t = threadIdx.x;
    const int wv = t >> 6;
    const int lane = t & 63;
    const int blk = (blockIdx.x & 7) * nbOver8 + (blockIdx.x >> 3);
    const int node = blk * 4 + wv;
    const int cntE = degS[node] - 1;
    const float degF = (float)(cntE + 1);
    const float dn = dinvS[node];
    const int2* sl = slots2 + startsS[node];
    float ax = 0.f, ay = 0.f, az = 0.f, aw = 0.f;
    int j = 0;
    for (; j + 8 <= cntE; j += 8) {
        int2 s[8];
#pragma unroll
        for (int u = 0; u < 8; ++u) s[u] = sl[j + u];
        float4 hv[8];
#pragma unroll
        for (int u = 0; u < 8; ++u)
            hv[u] = *(const float4*)&HL[(size_t)s[u].x * 256 + 4 * lane];
#pragma unroll
        for (int u = 0; u < 8; ++u) {
            float dv = __int_as_float(s[u].y);
            ax += dv * hv[u].x; ay += dv * hv[u].y;
            az += dv * hv[u].z; aw += dv * hv[u].w;
        }
    }
    for (; j + 4 <= cntE; j += 4) {
        int2 s[4];
#pragma unroll
        for (int u = 0; u < 4; ++u) s[u] = sl[j + u];
        float4 hv[4];
#pragma unroll
        for (int u = 0; u < 4; ++u)
            hv[u] = *(const float4*)&HL[(size_t)s[u].x * 256 + 4 * lane];
#pragma unroll
        for (int u = 0; u < 4; ++u) {
            float dv = __int_as_float(s[u].y);
            ax += dv * hv[u].x; ay += dv * hv[u].y;
            az += dv * hv[u].z; aw += dv * hv[u].w;
        }
    }
    for (; j < cntE; ++j) {
        int2 sv = sl[j];
        float dv = __int_as_float(sv.y);
        float4 hv = *(const float4*)&HL[(size_t)sv.x * 256 + 4 * lane];
        ax += dv * hv.x; ay += dv * hv.y; az += dv * hv.z; aw += dv * hv.w;
    }
    const float4 hn = *(const float4*)&HL[(size_t)node * 256 + 4 * lane];
    const float4 bi = *(const float4*)&bias[4 * lane];
    float4 v;
    v.x = ax * dn + hn.x / degF + bi.x;  v.x = fmaxf(v.x, 0.f);
    v.y = ay * dn + hn.y / degF + bi.y;  v.y = fmaxf(v.y, 0.f);
    v.z = az * dn + hn.z / degF + bi.z;  v.z = fmaxf(v.z, 0.f);
    v.w = aw * dn + hn.w / degF + bi.w;  v.w = fmaxf(v.w, 0.f);
    *(float4*)&H2[(size_t)node * 256 + 4 * lane] = v;
    *(float4*)&vrow[wv][4 * lane] = v;
    // same-wave LDS RAW: compiler inserts the lgkmcnt; no cross-wave sharing.
    float pr = 0.f, s2p = 0.f;
    for (int jj = 0; jj < 4; ++jj) {
        int f = lane + 64 * jj;
        float w = pw[f];
        pr += vrow[wv][f] * w;
        s2p += w * w;
    }
    for (int off = 32; off; off >>= 1) {
        pr += __shfl_down(pr, off, 64);
        s2p += __shfl_down(s2p, off, 64);
    }
    s2p = __shfl(s2p, 0, 64);
    if (lane == 0) score[node] = tanhf(pr / sqrtf(s2p));
}

// ---------------------------------------------------------------------------
// topk + cur update + pool + readout, FUSED (saves 2 launches/stage and the
// readout re-read pass). ss[n]/si_[n] after the sort are bit-identical to
// score[o]/kept order; pool product and max/mean chains keep the original
// n-ascending order -> bit-exact.
// ---------------------------------------------------------------------------
__global__ __launch_bounds__(256)
void topk_fused(const float* __restrict__ score, int npg, int k,
                const float* __restrict__ H2, float* __restrict__ OUT,
                float* __restrict__ outacc, int* __restrict__ cur, int first) {
    __shared__ float ss[256];
    __shared__ int si_[256];
    __shared__ int rankOf[256];
    const int g = blockIdx.x;
    const int t = threadIdx.x;
    if (t < npg) { ss[t] = score[g * npg + t]; si_[t] = t; }
    else         { ss[t] = -INFINITY; si_[t] = 0x7FFFFFFF; }
    for (int size = 2; size <= 256; size <<= 1) {
        for (int stride = size >> 1; stride > 0; stride >>= 1) {
            __syncthreads();
            int i = t, j = t ^ stride;
            if (j > i) {
                float a = ss[i], b = ss[j];
                int ia = si_[i], ib = si_[j];
                bool inOrder = (a > b) || (a == b && ia < ib);
                bool desc = ((i & size) == 0);
                if (desc ? !inOrder : inOrder) {
                    ss[i] = b; ss[j] = a; si_[i] = ib; si_[j] = ia;
                }
            }
        }
    }
    __syncthreads();
    rankOf[t] = -1;
    __syncthreads();
    if (t < k) rankOf[si_[t]] = t;
    __syncthreads();
    {
        int v = g * 256 + t;
        int c = cur[v];
        cur[v] = (c >= 0) ? rankOf[c] : -1;
    }
    // pool + readout: n-ascending, 4-way unrolled (k % 4 == 0 always)
    const size_t gb = (size_t)g * npg * 256;
    float mx = -INFINITY, sm = 0.f;
    for (int n = 0; n < k; n += 4) {
        float v0 = H2[gb + (size_t)si_[n + 0] * 256 + t] * ss[n + 0];
        float v1 = H2[gb + (size_t)si_[n + 1] * 256 + t] * ss[n + 1];
        float v2 = H2[gb + (size_t)si_[n + 2] * 256 + t] * ss[n + 2];
        float v3 = H2[gb + (size_t)si_[n + 3] * 256 + t] * ss[n + 3];
        size_t ob = ((size_t)g * k + n) * 256 + t;
        OUT[ob]       = v0;
        OUT[ob + 256] = v1;
        OUT[ob + 512] = v2;
        OUT[ob + 768] = v3;
        mx = fmaxf(mx, v0); sm += v0;
        mx = fmaxf(mx, v1); sm += v1;
        mx = fmaxf(mx, v2); sm += v2;
        mx = fmaxf(mx, v3); sm += v3;
    }
    float mean = sm / (float)k;
    if (first) {
        outacc[g * 512 + t] = mx;
        outacc[g * 512 + 256 + t] = mean;
    } else {
        outacc[g * 512 + t] += mx;
        outacc[g * 512 + 256 + t] += mean;
    }
}

__global__ __launch_bounds__(256)
void mlp_head(const float* __restrict__ outacc,
              const float* __restrict__ l1w, const float* __restrict__ l1b,
              const float* __restrict__ l2w, const float* __restrict__ l2b,
              const float* __restrict__ l3w, const float* __restrict__ l3b,
              float* __restrict__ out) {
    __shared__ float row[512];
    __shared__ float h1[256];
    __shared__ float h2[128];
    const int g = blockIdx.x;
    const int t = threadIdx.x;
    row[t] = outacc[g * 512 + t];
    row[256 + t] = outacc[g * 512 + 256 + t];
    __syncthreads();
    {
        float a = l1b[t];
        for (int j = 0; j < 512; ++j) a += row[j] * l1w[j * 256 + t];
        h1[t] = fmaxf(a, 0.f);
    }
    __syncthreads();
    if (t < 128) {
        float a2 = l2b[t];
        for (int j = 0; j < 256; ++j) a2 += h1[j] * l2w[j * 128 + t];
        h2[t] = fmaxf(a2, 0.f);
    }
    __syncthreads();
    if (t == 0) {
        float l0 = l3b[0], l1 = l3b[1];
        for (int j = 0; j < 128; ++j) {
            float h = h2[j];
            l0 += h * l3w[j * 2 + 0];
            l1 += h * l3w[j * 2 + 1];
        }
        float m = fmaxf(l0, l1);
        float lse = m + logf(expf(l0 - m) + expf(l1 - m));
        out[g * 2 + 0] = l0 - lse;
        out[g * 2 + 1] = l1 - lse;
    }
}

// ============================================================================
// Fallback: proven R15 monolith (used only if ws_size is too small)
// ============================================================================
__global__ __launch_bounds__(256, 1)
void gnn_mono(const float* __restrict__ x, const int* __restrict__ ei,
              const float* __restrict__ gw0, const float* __restrict__ gb0,
              const float* __restrict__ gw1, const float* __restrict__ gb1,
              const float* __restrict__ gw2, const float* __restrict__ gb2,
              const float* __restrict__ pw0, const float* __restrict__ pw1,
              const float* __restrict__ pw2,
              const float* __restrict__ l1w, const float* __restrict__ l1b,
              const float* __restrict__ l2w, const float* __restrict__ l2b,
              const float* __restrict__ l3w, const float* __restrict__ l3b,
              float* __restrict__ out, float* __restrict__ ws) {
    const int g = blockIdx.x;
    const int t = threadIdx.x;
    float* P = ws + (size_t)g * HF * 256;
    float* Q = ws + (size_t)G_GRAPHS * HF * 256 + (size_t)g * HF * 256;
    __shared__ int   eb[EPG];
    __shared__ int   slots[EPG];
    __shared__ int   curID[256];
    __shared__ int   cntL[256];
    __shared__ int   startL[256];
    __shared__ float degF[256];
    __shared__ float dinv[256];
    __shared__ float sa[256];
    __shared__ float ss[256];
    __shared__ int   si_[256];
    __shared__ float scoreV[256];
    __shared__ int   kept[128];
    __shared__ int   rankOf[256];
    __shared__ float row[512];
    for (int e = t; e < EPG; e += 256) {
        size_t idx = (size_t)g * EPG + e;
        eb[e] = ((ei[idx] - g * 256) << 8) | (ei[E_TOT + idx] - g * 256);
    }
    curID[t] = t;
    float accMx = 0.f, accMn = 0.f;
    const float* GW[3] = {gw0, gw1, gw2};
    const float* GB[3] = {gb0, gb1, gb2};
    const float* PW[3] = {pw0, pw1, pw2};
    const int kk[3] = {128, 64, 32};
    int npg = 256;
    __syncthreads();
    for (int s = 0; s < 3; ++s) {
        const int knext = kk[s];
        {
            const float* Wp = GW[s];
            const int K = (s == 0) ? FIN : HF;
            for (int n = 0; n < npg; ++n) {
                if (s == 0) { if (t < FIN) sa[t] = x[(size_t)(g * 256 + n) * FIN + t]; }
                else sa[t] = P[(size_t)n * HF + t];
                __syncthreads();
                float a = 0.f;
                for (int k2 = 0; k2 < K; ++k2) a += sa[k2] * Wp[k2 * HF + t];
                Q[(size_t)n * HF + t] = a;
                __syncthreads();
            }
        }
        cntL[t] = 0;
        __syncthreads();
        for (int e = t; e < EPG; e += 256) {
            int p = eb[e];
            int cu = curID[p >> 8], cv = curID[p & 255];
            if (cu >= 0 && cv >= 0) atomicAdd(&cntL[cv], 1);
        }
        __syncthreads();
        if (t == 0) { int run = 0; for (int i = 0; i < npg; ++i) { startL[i] = run; run += cntL[i]; } }
        __syncthreads();
        if (t < npg) {
            float d = (float)cntL[t] + 1.0f;
            degF[t] = d;
            dinv[t] = 1.0f / sqrtf(d);
            int c = startL[t];
            for (int e = 0; e < EPG; ++e) {
                int p = eb[e];
                int cu = curID[p >> 8], cv = curID[p & 255];
                if (cu >= 0 && cv >= 0 && cv == t) slots[c++] = e;
            }
        }
        __syncthreads();
        {
            const float bb = GB[s][t];
            for (int n = 0; n < npg; ++n) {
                float acc = 0.f;
                const int s0 = startL[n], s1 = s0 + cntL[n];
                for (int j = s0; j < s1; ++j) {
                    int scur = curID[eb[slots[j]] >> 8];
                    acc += dinv[scur] * Q[(size_t)scur * HF + t];
                }
                float v = acc * dinv[n] + Q[(size_t)n * HF + t] / degF[n] + bb;
                P[(size_t)n * HF + t] = fmaxf(v, 0.f);
            }
        }
        __syncthreads();
        {
            const float* pwp = PW[s];
            const int lane = t & 63, wv = t >> 6;
            float s2p = 0.f;
            for (int j = 0; j < 4; ++j) { float w = pwp[lane + 64 * j]; s2p += w * w; }
            for (int off = 32; off; off >>= 1) s2p += __shfl_down(s2p, off, 64);
            s2p = __shfl(s2p, 0, 64);
            const float nw = sqrtf(s2p);
            for (int n = wv; n < npg; n += 4) {
                float pr = 0.f;
                for (int j = 0; j < 4; ++j) { int f = lane + 64 * j; pr += P[(size_t)n * HF + f] * pwp[f]; }
                for (int off = 32; off; off >>= 1) pr += __shfl_down(pr, off, 64);
                if (lane == 0) scoreV[n] = tanhf(pr / nw);
            }
        }
        __syncthreads();
        if (t < npg) { ss[t] = scoreV[t]; si_[t] = t; }
        else         { ss[t] = -INFINITY; si_[t] = 0x7FFFFFFF; }
        for (int size = 2; size <= 256; size <<= 1) {
            for (int stride = size >> 1; stride > 0; stride >>= 1) {
                __syncthreads();
                int i = t, j = t ^ stride;
                if (j > i) {
                    float a = ss[i], b = ss[j];
                    int ia = si_[i], ib = si_[j];
                    bool inOrder = (a > b) || (a == b && ia < ib);
                    bool desc = ((i & size) == 0);
                    if (desc ? !inOrder : inOrder) { ss[i] = b; ss[j] = a; si_[i] = ib; si_[j] = ia; }
                }
            }
        }
        __syncthreads();
        if (t < knext) kept[t] = si_[t];
        __syncthreads();
        {
            float mx = -INFINITY, sm = 0.f;
            for (int n = 0; n < knext; ++n) {
                int o = kept[n];
                float vv = P[(size_t)o * HF + t] * scoreV[o];
                Q[(size_t)n * HF + t] = vv;
                mx = fmaxf(mx, vv);
                sm += vv;
            }
            accMx += mx;
            accMn += sm / (float)knext;
        }
        rankOf[t] = -1;
        __syncthreads();
        if (t < knext) rankOf[kept[t]] = t;
        __syncthreads();
        { int c = curID[t]; curID[t] = (c >= 0) ? rankOf[c] : -1; }
        __syncthreads();
        { float* tmp = P; P = Q; Q = tmp; }
        npg = knext;
    }
    row[t] = accMx;
    row[256 + t] = accMn;
    __syncthreads();
    { float a = l1b[t]; for (int j = 0; j < 512; ++j) a += row[j] * l1w[j * 256 + t]; scoreV[t] = fmaxf(a, 0.f); }
    __syncthreads();
    if (t < 128) { float a2 = l2b[t]; for (int j = 0; j < 256; ++j) a2 += scoreV[j] * l2w[j * 128 + t]; sa[t] = fmaxf(a2, 0.f); }
    __syncthreads();
    if (t == 0) {
        float l0 = l3b[0], l1 = l3b[1];
        for (int j = 0; j < 128; ++j) { float h = sa[j]; l0 += h * l3w[j * 2 + 0]; l1 += h * l3w[j * 2 + 1]; }
        float m = fmaxf(l0, l1);
        float lse = m + logf(expf(l0 - m) + expf(l1 - m));
        out[g * 2 + 0] = l0 - lse;
        out[g * 2 + 1] = l1 - lse;
    }
}

// ============================================================================
extern "C" void kernel_launch(void* const* d_in, const int* in_sizes, int n_in,
                              void* d_out, int out_size, void* d_ws, size_t ws_size,
                              hipStream_t stream) {
    const float* x   = (const float*)d_in[0];
    const int*   ei  = (const int*)d_in[1];
    const float* gw0 = (const float*)d_in[3];
    const float* gb0 = (const float*)d_in[4];
    const float* gw1 = (const float*)d_in[5];
    const float* gb1 = (const float*)d_in[6];
    const float* gw2 = (const float*)d_in[7];
    const float* gb2 = (const float*)d_in[8];
    const float* pw0 = (const float*)d_in[9];
    const float* pw1 = (const float*)d_in[10];
    const float* pw2 = (const float*)d_in[11];
    const float* l1w = (const float*)d_in[12];
    const float* l1b = (const float*)d_in[13];
    const float* l2w = (const float*)d_in[14];
    const float* l2b = (const float*)d_in[15];
    const float* l3w = (const float*)d_in[16];
    const float* l3b = (const float*)d_in[17];
    float* out = (float*)d_out;

    const size_t SLAB = (size_t)65536 * 256;
    char* p = (char*)d_ws;
    float* P      = (float*)p; p += SLAB * 4;
    float* Q      = (float*)p; p += SLAB * 4;
    int*   cur    = (int*)p;   p += (size_t)65536 * 4;
    int*   degS   = (int*)p;   p += (size_t)65536 * 4;
    float* dinvS  = (float*)p; p += (size_t)65536 * 4;
    int*   starts = (int*)p;   p += (size_t)65536 * 4;
    int2*  slots2 = (int2*)p;  p += (size_t)E_TOT * 8;
    float* score  = (float*)p; p += (size_t)65536 * 4;
    int*   kept   = (int*)p;   p += (size_t)32768 * 4;
    float* outacc = (float*)p; p += (size_t)G_GRAPHS * 512 * 4;
    const size_t needed = (size_t)(p - (char*)d_ws);

    if (ws_size < needed) {
        gnn_mono<<<G_GRAPHS, 256, 0, stream>>>(
            x, ei, gw0, gb0, gw1, gb1, gw2, gb2, pw0, pw1, pw2,
            l1w, l1b, l2w, l2b, l3w, l3b, out, (float*)d_ws);
        return;
    }

    init_cur<<<(G_GRAPHS * 256 + 255) / 256, 256, 0, stream>>>(cur);

    const int   npg[3] = {256, 128, 64};
    const int   kk[3]  = {128, 64, 32};
    const int   Ns[3]  = {65536, 32768, 16384};
    const float* GW[3] = {gw0, gw1, gw2};
    const float* GB[3] = {gb0, gb1, gb2};
    const float* PW[3] = {pw0, pw1, pw2};

    float* HLs[3]   = {P, Q, P};
    float* H2s[3]   = {Q, P, Q};
    float* POOLs[3] = {P, Q, P};

    for (int s = 0; s < 3; ++s) {
        const int n = Ns[s];
        const int k = kk[s];
        // 1) GEMM v8: 64x128 tile + async-STAGE split (issue-early/write-late)
        if (s == 0) {
            gemm_v8<FIN><<<dim3(n / 64, 2), 256, 0, stream>>>(x, GW[s], HLs[s]);
        } else {
            gemm_v8<HF><<<dim3(n / 64, 2), 256, 0, stream>>>(POOLs[s - 1], GW[s], HLs[s]);
        }
        // 2) CSR (parallel stable counting sort, packed slots)
        csr_build<<<G_GRAPHS, 256, 0, stream>>>(ei, cur, npg[s],
                                                degS, dinvS, starts, slots2);
        // 3) conv + score v2: wave-per-node, float4 gathers, no barriers
        agg_score2<<<n / 4, 256, 0, stream>>>(degS, dinvS, starts, slots2,
                                              HLs[s], H2s[s], GB[s], PW[s], score,
                                              n / 32);
        // 4-6) top-k + cur update + pool + readout, fused
        topk_fused<<<G_GRAPHS, 256, 0, stream>>>(score, npg[s], k,
                                                 H2s[s], POOLs[s], outacc, cur,
                                                 s == 0 ? 1 : 0);
    }

    mlp_head<<<G_GRAPHS, 256, 0, stream>>>(outacc, l1w, l1b, l2w, l2b, l3w, l3b, out);
}

// Round 6
// 431.962 us; speedup vs baseline: 1.4086x; 1.0563x over previous
//
#include <hip/hip_runtime.h>
#include <hip/hip_bf16.h>
#include <math.h>

#define G_GRAPHS 256
#define EPG 2048
#define E_TOT 524288
#define HF 256
#define FIN 128

// ============================================================================
__global__ void init_cur(int* __restrict__ cur) {
    int i = blockIdx.x * blockDim.x + threadIdx.x;
    if (i < G_GRAPHS * 256) cur[i] = i & 255;
}

// ---------------------------------------------------------------------------
// C[N x 256] = A[N x K] @ W[K x 256], fp32, k-ascending single-accumulator
// chains (bit-exact vs all previous versions).
// v9 = v8 + DOUBLE-BUFFERED LDS: one barrier per K-tile instead of two.
// R5 showed the remaining 45% idle is barrier drains: v8's barrier-after-
// compute exists only to protect the single buffer from the staging write.
// With two buffers, write_stage(cur^1) can't disturb waves reading cur, so
// that barrier vanishes; the one remaining barrier publishes the next tile.
//   * 64x128 tile, 4x8/thread, BK=32 (v7/v8-proven layouts).
//   * A transposed As[kk][row ^ (kq<<3)], stride 68 (2-way staging, bcast reads)
//   * W split halves Wa/Wb[32][68] (2-way staging, 2-way+bcast reads)
//   * LDS 52KB -> 3 blocks/CU (12 waves, >= current effective 2.65).
// ---------------------------------------------------------------------------
template <int K>
__global__ __launch_bounds__(256, 4)
void gemm_v9(const float* __restrict__ A, const float* __restrict__ W,
             float* __restrict__ C) {
    __shared__ __align__(16) float As[2][32 * 68];
    __shared__ __align__(16) float Wa[2][32 * 68];
    __shared__ __align__(16) float Wb[2][32 * 68];
    const int tid = threadIdx.x;
    const int tx = tid & 15;    // col groups: c0 + tx*4, c0 + 64 + tx*4
    const int ty = tid >> 4;    // rows r0 + ty*4 .. +3
    const int r0 = blockIdx.x * 64;
    const int c0 = blockIdx.y * 128;
    const int l8 = tid >> 3;    // 0..31 (A staging row-within-slab)
    const int kq = tid & 7;     // A staging float4 index along k
    const int wkk = tid >> 5;   // 0..7  (W staging kk base)
    const int wc = tid & 31;    // W staging float4 col index
    float acc[4][8] = {{0.f}};
    float4 va0, va1, vw0, vw1, vw2, vw3;

    auto load_regs = [&](int k0) {
        va0 = *(const float4*)&A[(size_t)(r0 + l8) * K + k0 + 4 * kq];
        va1 = *(const float4*)&A[(size_t)(r0 + 32 + l8) * K + k0 + 4 * kq];
        vw0 = *(const float4*)&W[(size_t)(k0 + 0  + wkk) * 256 + c0 + 4 * wc];
        vw1 = *(const float4*)&W[(size_t)(k0 + 8  + wkk) * 256 + c0 + 4 * wc];
        vw2 = *(const float4*)&W[(size_t)(k0 + 16 + wkk) * 256 + c0 + 4 * wc];
        vw3 = *(const float4*)&W[(size_t)(k0 + 24 + wkk) * 256 + c0 + 4 * wc];
    };
    auto write_stage = [&](int b) {
        // A transposed + kq-XOR swizzle (staging 2-way free, reads broadcast)
        {
            int rs = l8 ^ (kq << 3);
            As[b][(4 * kq + 0) * 68 + rs] = va0.x;
            As[b][(4 * kq + 1) * 68 + rs] = va0.y;
            As[b][(4 * kq + 2) * 68 + rs] = va0.z;
            As[b][(4 * kq + 3) * 68 + rs] = va0.w;
        }
        {
            int rs = (32 + l8) ^ (kq << 3);
            As[b][(4 * kq + 0) * 68 + rs] = va1.x;
            As[b][(4 * kq + 1) * 68 + rs] = va1.y;
            As[b][(4 * kq + 2) * 68 + rs] = va1.z;
            As[b][(4 * kq + 3) * 68 + rs] = va1.w;
        }
        // W split halves (stride 68): staging 2-way, reads 2-way + broadcast
        if (wc < 16) {
            *(float4*)&Wa[b][(0  + wkk) * 68 + 4 * wc] = vw0;
            *(float4*)&Wa[b][(8  + wkk) * 68 + 4 * wc] = vw1;
            *(float4*)&Wa[b][(16 + wkk) * 68 + 4 * wc] = vw2;
            *(float4*)&Wa[b][(24 + wkk) * 68 + 4 * wc] = vw3;
        } else {
            *(float4*)&Wb[b][(0  + wkk) * 68 + 4 * (wc - 16)] = vw0;
            *(float4*)&Wb[b][(8  + wkk) * 68 + 4 * (wc - 16)] = vw1;
            *(float4*)&Wb[b][(16 + wkk) * 68 + 4 * (wc - 16)] = vw2;
            *(float4*)&Wb[b][(24 + wkk) * 68 + 4 * (wc - 16)] = vw3;
        }
    };
    auto compute = [&](int b) {
#pragma unroll 4
        for (int kk = 0; kk < 32; ++kk) {
            const int g = (ty * 4) ^ ((kk >> 2) << 3);
            const float4 a0 = *(const float4*)&As[b][kk * 68 + g];
            const float4 w0 = *(const float4*)&Wa[b][kk * 68 + tx * 4];
            const float4 w1 = *(const float4*)&Wb[b][kk * 68 + tx * 4];
            float av[4] = {a0.x, a0.y, a0.z, a0.w};
            float wv_[8] = {w0.x, w0.y, w0.z, w0.w, w1.x, w1.y, w1.z, w1.w};
#pragma unroll
            for (int i = 0; i < 4; ++i)
#pragma unroll
                for (int j = 0; j < 8; ++j)
                    acc[i][j] += av[i] * wv_[j];
        }
    };

    load_regs(0);
    write_stage(0);
    __syncthreads();
    int cur = 0;
    for (int k0 = 0; k0 < K - 32; k0 += 32) {
        load_regs(k0 + 32);    // issue early: in flight under compute
        compute(cur);
        write_stage(cur ^ 1);  // other buffer: no read/write hazard, no barrier
        __syncthreads();       // publish next buffer
        cur ^= 1;
    }
    compute(cur);              // last tile

#pragma unroll
    for (int i = 0; i < 4; ++i) {
        float4 v0 = make_float4(acc[i][0], acc[i][1], acc[i][2], acc[i][3]);
        float4 v1 = make_float4(acc[i][4], acc[i][5], acc[i][6], acc[i][7]);
        size_t base = (size_t)(r0 + ty * 4 + i) * 256 + c0 + tx * 4;
        *(float4*)&C[base] = v0;
        *(float4*)&C[base + 64] = v1;
    }
}

// ---------------------------------------------------------------------------
// Parallel STABLE counting-sort CSR with packed (src, dinv_src) slots.
// ---------------------------------------------------------------------------
__global__ __launch_bounds__(256)
void csr_build(const int* __restrict__ ei, const int* __restrict__ cur, int npg,
               int* __restrict__ degS, float* __restrict__ dinvS,
               int* __restrict__ startsS, int2* __restrict__ slots2) {
    __shared__ int cul[EPG];
    __shared__ short dstv[EPG];
    __shared__ unsigned char rnk[EPG];
    __shared__ int h[32][256];
    __shared__ int cnt[256];
    __shared__ int st[256];
    const int g = blockIdx.x;
    const int t = threadIdx.x;
    const int lane = t & 63;
    const int wv = t >> 6;

    for (int i = t; i < 32 * 256; i += 256) ((int*)h)[i] = 0;
    for (int e = t; e < EPG; e += 256) {
        size_t idx = (size_t)g * EPG + e;
        int cu = cur[g * 256 + (ei[idx] - g * 256)];
        int cv = cur[g * 256 + (ei[E_TOT + idx] - g * 256)];
        bool valid = (cu >= 0 && cv >= 0);
        cul[e] = cu;
        dstv[e] = valid ? (short)cv : (short)256;
    }
    __syncthreads();
    for (int c = wv; c < 32; c += 4) {
        int e = c * 64 + lane;
        int d = (int)dstv[e];
        unsigned long long m = ~0ULL;
#pragma unroll
        for (int b = 0; b < 9; ++b) {
            unsigned long long bb = __ballot((d >> b) & 1);
            m &= ((d >> b) & 1) ? bb : ~bb;
        }
        int r = __popcll(m & ((1ULL << lane) - 1ULL));
        rnk[e] = (unsigned char)r;
        if (r == 0 && d < 256) h[c][d] = __popcll(m);
    }
    __syncthreads();
    if (t < npg) {
        int run = 0;
        for (int c = 0; c < 32; ++c) { int v = h[c][t]; h[c][t] = run; run += v; }
        cnt[t] = run;
        degS[g * npg + t] = run + 1;
        dinvS[g * npg + t] = 1.0f / sqrtf((float)(run + 1));
    }
    __syncthreads();
    if (t == 0) {
        int run = 0;
        for (int i = 0; i < npg; ++i) { st[i] = run; run += cnt[i]; }
    }
    __syncthreads();
    if (t < npg) startsS[g * npg + t] = g * EPG + st[t];
    for (int e = t; e < EPG; e += 256) {
        int d = (int)dstv[e];
        if (d < npg) {
            int slot = st[d] + h[e >> 6][d] + (int)rnk[e];
            int cu = cul[e];
            float dv = 1.0f / sqrtf((float)(cnt[cu] + 1));   // == dinvS[src]
            slots2[g * EPG + slot] = make_int2(g * npg + cu, __float_as_int(dv));
        }
    }
}

// ---------------------------------------------------------------------------
// conv + relu + pool score, v2: ONE WAVE PER NODE, float4 per lane.
// (R2-proven: bit-exact, dropped agg from 70.6us out of the top-5.)
// ---------------------------------------------------------------------------
__global__ __launch_bounds__(256)
void agg_score2(const int* __restrict__ degS, const float* __restrict__ dinvS,
                const int* __restrict__ startsS, const int2* __restrict__ slots2,
                const float* __restrict__ HL, float* __restrict__ H2,
                const float* __restrict__ bias, const float* __restrict__ pw,
                float* __restrict__ score, int nbOver8) {
    __shared__ float vrow[4][256];
    const int t = threadIdx.x;
    const int wv = t >> 6;
    const int lane = t & 63;
    const int blk = (blockIdx.x & 7) * nbOver8 + (blockIdx.x >> 3);
    const int node = blk * 4 + wv;
    const int cntE = degS[node] - 1;
    const float degF = (float)(cntE + 1);
    const float dn = dinvS[node];
    const int2* sl = slots2 + startsS[node];
    float ax = 0.f, ay = 0.f, az = 0.f, aw = 0.f;
    int j = 0;
    for (; j + 8 <= cntE; j += 8) {
        int2 s[8];
#pragma unroll
        for (int u = 0; u < 8; ++u) s[u] = sl[j + u];
        float4 hv[8];
#pragma unroll
        for (int u = 0; u < 8; ++u)
            hv[u] = *(const float4*)&HL[(size_t)s[u].x * 256 + 4 * lane];
#pragma unroll
        for (int u = 0; u < 8; ++u) {
            float dv = __int_as_float(s[u].y);
            ax += dv * hv[u].x; ay += dv * hv[u].y;
            az += dv * hv[u].z; aw += dv * hv[u].w;
        }
    }
    for (; j + 4 <= cntE; j += 4) {
        int2 s[4];
#pragma unroll
        for (int u = 0; u < 4; ++u) s[u] = sl[j + u];
        float4 hv[4];
#pragma unroll
        for (int u = 0; u < 4; ++u)
            hv[u] = *(const float4*)&HL[(size_t)s[u].x * 256 + 4 * lane];
#pragma unroll
        for (int u = 0; u < 4; ++u) {
            float dv = __int_as_float(s[u].y);
            ax += dv * hv[u].x; ay += dv * hv[u].y;
            az += dv * hv[u].z; aw += dv * hv[u].w;
        }
    }
    for (; j < cntE; ++j) {
        int2 sv = sl[j];
        float dv = __int_as_float(sv.y);
        float4 hv = *(const float4*)&HL[(size_t)sv.x * 256 + 4 * lane];
        ax += dv * hv.x; ay += dv * hv.y; az += dv * hv.z; aw += dv * hv.w;
    }
    const float4 hn = *(const float4*)&HL[(size_t)node * 256 + 4 * lane];
    const float4 bi = *(const float4*)&bias[4 * lane];
    float4 v;
    v.x = ax * dn + hn.x / degF + bi.x;  v.x = fmaxf(v.x, 0.f);
    v.y = ay * dn + hn.y / degF + bi.y;  v.y = fmaxf(v.y, 0.f);
    v.z = az * dn + hn.z / degF + bi.z;  v.z = fmaxf(v.z, 0.f);
    v.w = aw * dn + hn.w / degF + bi.w;  v.w = fmaxf(v.w, 0.f);
    *(float4*)&H2[(size_t)node * 256 + 4 * lane] = v;
    *(float4*)&vrow[wv][4 * lane] = v;
    // same-wave LDS RAW: compiler inserts the lgkmcnt; no cross-wave sharing.
    float pr = 0.f, s2p = 0.f;
    for (int jj = 0; jj < 4; ++jj) {
        int f = lane + 64 * jj;
        float w = pw[f];
        pr += vrow[wv][f] * w;
        s2p += w * w;
    }
    for (int off = 32; off; off >>= 1) {
        pr += __shfl_down(pr, off, 64);
        s2p += __shfl_down(s2p, off, 64);
    }
    s2p = __shfl(s2p, 0, 64);
    if (lane == 0) score[node] = tanhf(pr / sqrtf(s2p));
}

// ---------------------------------------------------------------------------
// topk + cur update + pool + readout, FUSED (R5-proven, bit-exact).
// ---------------------------------------------------------------------------
__global__ __launch_bounds__(256)
void topk_fused(const float* __restrict__ score, int npg, int k,
                const float* __restrict__ H2, float* __restrict__ OUT,
                float* __restrict__ outacc, int* __restrict__ cur, int first) {
    __shared__ float ss[256];
    __shared__ int si_[256];
    __shared__ int rankOf[256];
    const int g = blockIdx.x;
    const int t = threadIdx.x;
    if (t < npg) { ss[t] = score[g * npg + t]; si_[t] = t; }
    else         { ss[t] = -INFINITY; si_[t] = 0x7FFFFFFF; }
    for (int size = 2; size <= 256; size <<= 1) {
        for (int stride = size >> 1; stride > 0; stride >>= 1) {
            __syncthreads();
            int i = t, j = t ^ stride;
            if (j > i) {
                float a = ss[i], b = ss[j];
                int ia = si_[i], ib = si_[j];
                bool inOrder = (a > b) || (a == b && ia < ib);
                bool desc = ((i & size) == 0);
                if (desc ? !inOrder : inOrder) {
                    ss[i] = b; ss[j] = a; si_[i] = ib; si_[j] = ia;
                }
            }
        }
    }
    __syncthreads();
    rankOf[t] = -1;
    __syncthreads();
    if (t < k) rankOf[si_[t]] = t;
    __syncthreads();
    {
        int v = g * 256 + t;
        int c = cur[v];
        cur[v] = (c >= 0) ? rankOf[c] : -1;
    }
    // pool + readout: n-ascending, 4-way unrolled (k % 4 == 0 always)
    const size_t gb = (size_t)g * npg * 256;
    float mx = -INFINITY, sm = 0.f;
    for (int n = 0; n < k; n += 4) {
        float v0 = H2[gb + (size_t)si_[n + 0] * 256 + t] * ss[n + 0];
        float v1 = H2[gb + (size_t)si_[n + 1] * 256 + t] * ss[n + 1];
        float v2 = H2[gb + (size_t)si_[n + 2] * 256 + t] * ss[n + 2];
        float v3 = H2[gb + (size_t)si_[n + 3] * 256 + t] * ss[n + 3];
        size_t ob = ((size_t)g * k + n) * 256 + t;
        OUT[ob]       = v0;
        OUT[ob + 256] = v1;
        OUT[ob + 512] = v2;
        OUT[ob + 768] = v3;
        mx = fmaxf(mx, v0); sm += v0;
        mx = fmaxf(mx, v1); sm += v1;
        mx = fmaxf(mx, v2); sm += v2;
        mx = fmaxf(mx, v3); sm += v3;
    }
    float mean = sm / (float)k;
    if (first) {
        outacc[g * 512 + t] = mx;
        outacc[g * 512 + 256 + t] = mean;
    } else {
        outacc[g * 512 + t] += mx;
        outacc[g * 512 + 256 + t] += mean;
    }
}

__global__ __launch_bounds__(256)
void mlp_head(const float* __restrict__ outacc,
              const float* __restrict__ l1w, const float* __restrict__ l1b,
              const float* __restrict__ l2w, const float* __restrict__ l2b,
              const float* __restrict__ l3w, const float* __restrict__ l3b,
              float* __restrict__ out) {
    __shared__ float row[512];
    __shared__ float h1[256];
    __shared__ float h2[128];
    const int g = blockIdx.x;
    const int t = threadIdx.x;
    row[t] = outacc[g * 512 + t];
    row[256 + t] = outacc[g * 512 + 256 + t];
    __syncthreads();
    {
        float a = l1b[t];
        for (int j = 0; j < 512; ++j) a += row[j] * l1w[j * 256 + t];
        h1[t] = fmaxf(a, 0.f);
    }
    __syncthreads();
    if (t < 128) {
        float a2 = l2b[t];
        for (int j = 0; j < 256; ++j) a2 += h1[j] * l2w[j * 128 + t];
        h2[t] = fmaxf(a2, 0.f);
    }
    __syncthreads();
    if (t == 0) {
        float l0 = l3b[0], l1 = l3b[1];
        for (int j = 0; j < 128; ++j) {
            float h = h2[j];
            l0 += h * l3w[j * 2 + 0];
            l1 += h * l3w[j * 2 + 1];
        }
        float m = fmaxf(l0, l1);
        float lse = m + logf(expf(l0 - m) + expf(l1 - m));
        out[g * 2 + 0] = l0 - lse;
        out[g * 2 + 1] = l1 - lse;
    }
}

// ============================================================================
// Fallback: proven R15 monolith (used only if ws_size is too small)
// ============================================================================
__global__ __launch_bounds__(256, 1)
void gnn_mono(const float* __restrict__ x, const int* __restrict__ ei,
              const float* __restrict__ gw0, const float* __restrict__ gb0,
              const float* __restrict__ gw1, const float* __restrict__ gb1,
              const float* __restrict__ gw2, const float* __restrict__ gb2,
              const float* __restrict__ pw0, const float* __restrict__ pw1,
              const float* __restrict__ pw2,
              const float* __restrict__ l1w, const float* __restrict__ l1b,
              const float* __restrict__ l2w, const float* __restrict__ l2b,
              const float* __restrict__ l3w, const float* __restrict__ l3b,
              float* __restrict__ out, float* __restrict__ ws) {
    const int g = blockIdx.x;
    const int t = threadIdx.x;
    float* P = ws + (size_t)g * HF * 256;
    float* Q = ws + (size_t)G_GRAPHS * HF * 256 + (size_t)g * HF * 256;
    __shared__ int   eb[EPG];
    __shared__ int   slots[EPG];
    __shared__ int   curID[256];
    __shared__ int   cntL[256];
    __shared__ int   startL[256];
    __shared__ float degF[256];
    __shared__ float dinv[256];
    __shared__ float sa[256];
    __shared__ float ss[256];
    __shared__ int   si_[256];
    __shared__ float scoreV[256];
    __shared__ int   kept[128];
    __shared__ int   rankOf[256];
    __shared__ float row[512];
    for (int e = t; e < EPG; e += 256) {
        size_t idx = (size_t)g * EPG + e;
        eb[e] = ((ei[idx] - g * 256) << 8) | (ei[E_TOT + idx] - g * 256);
    }
    curID[t] = t;
    float accMx = 0.f, accMn = 0.f;
    const float* GW[3] = {gw0, gw1, gw2};
    const float* GB[3] = {gb0, gb1, gb2};
    const float* PW[3] = {pw0, pw1, pw2};
    const int kk[3] = {128, 64, 32};
    int npg = 256;
    __syncthreads();
    for (int s = 0; s < 3; ++s) {
        const int knext = kk[s];
        {
            const float* Wp = GW[s];
            const int K = (s == 0) ? FIN : HF;
            for (int n = 0; n < npg; ++n) {
                if (s == 0) { if (t < FIN) sa[t] = x[(size_t)(g * 256 + n) * FIN + t]; }
                else sa[t] = P[(size_t)n * HF + t];
                __syncthreads();
                float a = 0.f;
                for (int k2 = 0; k2 < K; ++k2) a += sa[k2] * Wp[k2 * HF + t];
                Q[(size_t)n * HF + t] = a;
                __syncthreads();
            }
        }
        cntL[t] = 0;
        __syncthreads();
        for (int e = t; e < EPG; e += 256) {
            int p = eb[e];
            int cu = curID[p >> 8], cv = curID[p & 255];
            if (cu >= 0 && cv >= 0) atomicAdd(&cntL[cv], 1);
        }
        __syncthreads();
        if (t == 0) { int run = 0; for (int i = 0; i < npg; ++i) { startL[i] = run; run += cntL[i]; } }
        __syncthreads();
        if (t < npg) {
            float d = (float)cntL[t] + 1.0f;
            degF[t] = d;
            dinv[t] = 1.0f / sqrtf(d);
            int c = startL[t];
            for (int e = 0; e < EPG; ++e) {
                int p = eb[e];
                int cu = curID[p >> 8], cv = curID[p & 255];
                if (cu >= 0 && cv >= 0 && cv == t) slots[c++] = e;
            }
        }
        __syncthreads();
        {
            const float bb = GB[s][t];
            for (int n = 0; n < npg; ++n) {
                float acc = 0.f;
                const int s0 = startL[n], s1 = s0 + cntL[n];
                for (int j = s0; j < s1; ++j) {
                    int scur = curID[eb[slots[j]] >> 8];
                    acc += dinv[scur] * Q[(size_t)scur * HF + t];
                }
                float v = acc * dinv[n] + Q[(size_t)n * HF + t] / degF[n] + bb;
                P[(size_t)n * HF + t] = fmaxf(v, 0.f);
            }
        }
        __syncthreads();
        {
            const float* pwp = PW[s];
            const int lane = t & 63, wv = t >> 6;
            float s2p = 0.f;
            for (int j = 0; j < 4; ++j) { float w = pwp[lane + 64 * j]; s2p += w * w; }
            for (int off = 32; off; off >>= 1) s2p += __shfl_down(s2p, off, 64);
            s2p = __shfl(s2p, 0, 64);
            const float nw = sqrtf(s2p);
            for (int n = wv; n < npg; n += 4) {
                float pr = 0.f;
                for (int j = 0; j < 4; ++j) { int f = lane + 64 * j; pr += P[(size_t)n * HF + f] * pwp[f]; }
                for (int off = 32; off; off >>= 1) pr += __shfl_down(pr, off, 64);
                if (lane == 0) scoreV[n] = tanhf(pr / nw);
            }
        }
        __syncthreads();
        if (t < npg) { ss[t] = scoreV[t]; si_[t] = t; }
        else         { ss[t] = -INFINITY; si_[t] = 0x7FFFFFFF; }
        for (int size = 2; size <= 256; size <<= 1) {
            for (int stride = size >> 1; stride > 0; stride >>= 1) {
                __syncthreads();
                int i = t, j = t ^ stride;
                if (j > i) {
                    float a = ss[i], b = ss[j];
                    int ia = si_[i], ib = si_[j];
                    bool inOrder = (a > b) || (a == b && ia < ib);
                    bool desc = ((i & size) == 0);
                    if (desc ? !inOrder : inOrder) { ss[i] = b; ss[j] = a; si_[i] = ib; si_[j] = ia; }
                }
            }
        }
        __syncthreads();
        if (t < knext) kept[t] = si_[t];
        __syncthreads();
        {
            float mx = -INFINITY, sm = 0.f;
            for (int n = 0; n < knext; ++n) {
                int o = kept[n];
                float vv = P[(size_t)o * HF + t] * scoreV[o];
                Q[(size_t)n * HF + t] = vv;
                mx = fmaxf(mx, vv);
                sm += vv;
            }
            accMx += mx;
            accMn += sm / (float)knext;
        }
        rankOf[t] = -1;
        __syncthreads();
        if (t < knext) rankOf[kept[t]] = t;
        __syncthreads();
        { int c = curID[t]; curID[t] = (c >= 0) ? rankOf[c] : -1; }
        __syncthreads();
        { float* tmp = P; P = Q; Q = tmp; }
        npg = knext;
    }
    row[t] = accMx;
    row[256 + t] = accMn;
    __syncthreads();
    { float a = l1b[t]; for (int j = 0; j < 512; ++j) a += row[j] * l1w[j * 256 + t]; scoreV[t] = fmaxf(a, 0.f); }
    __syncthreads();
    if (t < 128) { float a2 = l2b[t]; for (int j = 0; j < 256; ++j) a2 += scoreV[j] * l2w[j * 128 + t]; sa[t] = fmaxf(a2, 0.f); }
    __syncthreads();
    if (t == 0) {
        float l0 = l3b[0], l1 = l3b[1];
        for (int j = 0; j < 128; ++j) { float h = sa[j]; l0 += h * l3w[j * 2 + 0]; l1 += h * l3w[j * 2 + 1]; }
        float m = fmaxf(l0, l1);
        float lse = m + logf(expf(l0 - m) + expf(l1 - m));
        out[g * 2 + 0] = l0 - lse;
        out[g * 2 + 1] = l1 - lse;
    }
}

// ============================================================================
extern "C" void kernel_launch(void* const* d_in, const int* in_sizes, int n_in,
                              void* d_out, int out_size, void* d_ws, size_t ws_size,
                              hipStream_t stream) {
    const float* x   = (const float*)d_in[0];
    const int*   ei  = (const int*)d_in[1];
    const float* gw0 = (const float*)d_in[3];
    const float* gb0 = (const float*)d_in[4];
    const float* gw1 = (const float*)d_in[5];
    const float* gb1 = (const float*)d_in[6];
    const float* gw2 = (const float*)d_in[7];
    const float* gb2 = (const float*)d_in[8];
    const float* pw0 = (const float*)d_in[9];
    const float* pw1 = (const float*)d_in[10];
    const float* pw2 = (const float*)d_in[11];
    const float* l1w = (const float*)d_in[12];
    const float* l1b = (const float*)d_in[13];
    const float* l2w = (const float*)d_in[14];
    const float* l2b = (const float*)d_in[15];
    const float* l3w = (const float*)d_in[16];
    const float* l3b = (const float*)d_in[17];
    float* out = (float*)d_out;

    const size_t SLAB = (size_t)65536 * 256;
    char* p = (char*)d_ws;
    float* P      = (float*)p; p += SLAB * 4;
    float* Q      = (float*)p; p += SLAB * 4;
    int*   cur    = (int*)p;   p += (size_t)65536 * 4;
    int*   degS   = (int*)p;   p += (size_t)65536 * 4;
    float* dinvS  = (float*)p; p += (size_t)65536 * 4;
    int*   starts = (int*)p;   p += (size_t)65536 * 4;
    int2*  slots2 = (int2*)p;  p += (size_t)E_TOT * 8;
    float* score  = (float*)p; p += (size_t)65536 * 4;
    int*   kept   = (int*)p;   p += (size_t)32768 * 4;
    float* outacc = (float*)p; p += (size_t)G_GRAPHS * 512 * 4;
    const size_t needed = (size_t)(p - (char*)d_ws);

    if (ws_size < needed) {
        gnn_mono<<<G_GRAPHS, 256, 0, stream>>>(
            x, ei, gw0, gb0, gw1, gb1, gw2, gb2, pw0, pw1, pw2,
            l1w, l1b, l2w, l2b, l3w, l3b, out, (float*)d_ws);
        return;
    }

    init_cur<<<(G_GRAPHS * 256 + 255) / 256, 256, 0, stream>>>(cur);

    const int   npg[3] = {256, 128, 64};
    const int   kk[3]  = {128, 64, 32};
    const int   Ns[3]  = {65536, 32768, 16384};
    const float* GW[3] = {gw0, gw1, gw2};
    const float* GB[3] = {gb0, gb1, gb2};
    const float* PW[3] = {pw0, pw1, pw2};

    float* HLs[3]   = {P, Q, P};
    float* H2s[3]   = {Q, P, Q};
    float* POOLs[3] = {P, Q, P};

    for (int s = 0; s < 3; ++s) {
        const int n = Ns[s];
        const int k = kk[s];
        // 1) GEMM v9: double-buffered LDS, one barrier per K-tile
        if (s == 0) {
            gemm_v9<FIN><<<dim3(n / 64, 2), 256, 0, stream>>>(x, GW[s], HLs[s]);
        } else {
            gemm_v9<HF><<<dim3(n / 64, 2), 256, 0, stream>>>(POOLs[s - 1], GW[s], HLs[s]);
        }
        // 2) CSR (parallel stable counting sort, packed slots)
        csr_build<<<G_GRAPHS, 256, 0, stream>>>(ei, cur, npg[s],
                                                degS, dinvS, starts, slots2);
        // 3) conv + score v2: wave-per-node, float4 gathers, no barriers
        agg_score2<<<n / 4, 256, 0, stream>>>(degS, dinvS, starts, slots2,
                                              HLs[s], H2s[s], GB[s], PW[s], score,
                                              n / 32);
        // 4-6) top-k + cur update + pool + readout, fused
        topk_fused<<<G_GRAPHS, 256, 0, stream>>>(score, npg[s], k,
                                                 H2s[s], POOLs[s], outacc, cur,
                                                 s == 0 ? 1 : 0);
    }

    mlp_head<<<G_GRAPHS, 256, 0, stream>>>(outacc, l1w, l1b, l2w, l2b, l3w, l3b, out);
}